// Round 1
// baseline (26223.792 us; speedup 1.0000x reference)
//
#include <hip/hip_runtime.h>
#include <hip/hip_bf16.h>

typedef __attribute__((ext_vector_type(8))) short short8;
typedef __attribute__((ext_vector_type(4))) float f32x4;
typedef unsigned short u16;
typedef unsigned int u32;

#define MFMA_BF16(a, b, c) __builtin_amdgcn_mfma_f32_16x16x32_bf16((a), (b), (c), 0, 0, 0)

// ---------------- workspace layout (bytes) ----------------
static constexpr size_t OFF_W   = 0;                       // 4 x [4096][1024] bf16 = 32MB (Wi0,Wh0,Wi1,Wh1)
static constexpr size_t OFF_B0  = 33554432;                // 4096 f32 (bi0+bh0)
static constexpr size_t OFF_B1  = OFF_B0 + 16384;          // 4096 f32 (bi1+bh1)
static constexpr size_t OFF_H0  = OFF_B1 + 16384;          // 2 x [32][1024] bf16 (double buffer)
static constexpr size_t OFF_H1  = OFF_H0 + 131072;         // 2 x [32][1024] bf16
static constexpr size_t OFF_H1F = OFF_H1 + 131072;         // [32][1024] f32 (final h1)
static constexpr size_t OFF_BAR = OFF_H1F + 131072;        // flags[256] u32 + gen u32 (own line)
static constexpr size_t OFF_XE  = OFF_BAR + 2048;          // [16384][1024] bf16 = 32MB
static constexpr size_t OFF_X0  = OFF_XE + 33554432;       // [16384][4096] bf16 = 128MB
static constexpr size_t WS_NEED = OFF_X0 + 134217728;      // ~192.5 MB

// ---------------- helpers ----------------
__device__ __forceinline__ u16 f2bf(float f) {
  u32 x = __builtin_bit_cast(u32, f);
  x += 0x7fffu + ((x >> 16) & 1u);   // RNE (inputs are finite)
  return (u16)(x >> 16);
}
__device__ __forceinline__ float bf2f(u16 u) {
  return __builtin_bit_cast(float, (u32)u << 16);
}
__device__ __forceinline__ float sigm(float x) { return 1.f / (1.f + expf(-x)); }

__device__ __forceinline__ void gload_lds16(const u16* gsrc, u16* ldst) {
  __builtin_amdgcn_global_load_lds(
      (__attribute__((address_space(1))) void*)(u16*)gsrc,
      (__attribute__((address_space(3))) void*)ldst, 16, 0, 0);
}

// ---------------- prep: fp32 weights -> bf16 ----------------
__global__ void prep_w_kernel(const float* __restrict__ Wi0, const float* __restrict__ Wh0,
                              const float* __restrict__ Wi1, const float* __restrict__ Wh1,
                              u16* __restrict__ dst) {
  size_t e = ((size_t)blockIdx.x * 256 + threadIdx.x) * 4;   // 16M elements total
  int mat = (int)(e >> 22);
  size_t off = e & ((1ull << 22) - 1);
  const float* src = (mat == 0) ? Wi0 : (mat == 1) ? Wh0 : (mat == 2) ? Wi1 : Wh1;
  float4 v = *(const float4*)(src + off);
  ushort4 o;
  o.x = f2bf(v.x); o.y = f2bf(v.y); o.z = f2bf(v.z); o.w = f2bf(v.w);
  *(ushort4*)(dst + e) = o;
}

__global__ void prep_b_kernel(const float* __restrict__ bi0, const float* __restrict__ bh0,
                              const float* __restrict__ bi1, const float* __restrict__ bh1,
                              float* __restrict__ b0, float* __restrict__ b1) {
  int i = blockIdx.x * 256 + threadIdx.x;   // 4096
  b0[i] = bi0[i] + bh0[i];
  b1[i] = bi1[i] + bh1[i];
}

// ---------------- embedding gather: xe[t*32+b][e] = emb[x[b][t]][e] (bf16) ----------------
__global__ void embed_kernel(const int* __restrict__ x, const float* __restrict__ emb,
                             u16* __restrict__ xe) {
  int m = blockIdx.x;            // m = t*32 + b
  int b = m & 31, t = m >> 5;
  int id = x[b * 512 + t];
  float4 v = ((const float4*)(emb + (size_t)id * 1024))[threadIdx.x];
  ushort4 o;
  o.x = f2bf(v.x); o.y = f2bf(v.y); o.z = f2bf(v.z); o.w = f2bf(v.w);
  *(ushort4*)(xe + (size_t)m * 1024 + threadIdx.x * 4) = o;
}

// ---------------- X0 GEMM: [16384,1024] x [4096,1024]^T -> bf16 [16384][4096] (+bias) ----------------
// 128x128 tile, BK=64, 4 waves, double-buffered LDS via global_load_lds(16B),
// XOR-swizzled K-chunks (chunk u holds data chunk u^(row&7)) for conflict-free ds_read_b128.
__global__ void x0_gemm_kernel(const u16* __restrict__ A, const u16* __restrict__ W,
                               const float* __restrict__ bias, u16* __restrict__ C) {
  __shared__ u16 lds[2][2][8192];   // [buf][A/B][128 rows x 64 cols]
  const int tid = threadIdx.x, l = tid & 63, w = tid >> 6;
  const int n0 = blockIdx.x * 128, m0 = blockIdx.y * 128;
  const int wm = w >> 1, wn = w & 1;
  const int row8 = l >> 3, u = l & 7;

  f32x4 acc[4][4];
#pragma unroll
  for (int a1 = 0; a1 < 4; ++a1)
#pragma unroll
    for (int a2 = 0; a2 < 4; ++a2) acc[a1][a2] = (f32x4){0.f, 0.f, 0.f, 0.f};

  auto stage = [&](int buf, int kt) {
    const int k0 = kt * 64;
#pragma unroll
    for (int q = 0; q < 4; ++q) {
      const int ld = w * 4 + q;
      const int row = ld * 8 + row8;
      const int sw = (u ^ (row & 7)) * 8;
      gload_lds16(A + (size_t)(m0 + row) * 1024 + k0 + sw, &lds[buf][0][ld * 512]);
      gload_lds16(W + (size_t)(n0 + row) * 1024 + k0 + sw, &lds[buf][1][ld * 512]);
    }
  };

  stage(0, 0);
  __syncthreads();

  for (int kt = 0; kt < 16; ++kt) {
    const int buf = kt & 1;
    if (kt < 15) stage(buf ^ 1, kt + 1);
    const u16* la = lds[buf][0];
    const u16* lb = lds[buf][1];
#pragma unroll
    for (int kk = 0; kk < 2; ++kk) {
      const int c = kk * 4 + (l >> 4);
      const int csw = (c ^ (l & 7)) * 8;    // row&7 == l&7 for all frag rows
      short8 af[4], bf[4];
#pragma unroll
      for (int mi = 0; mi < 4; ++mi) {
        int row = wm * 64 + mi * 16 + (l & 15);
        af[mi] = *(const short8*)(la + row * 64 + csw);
      }
#pragma unroll
      for (int ni = 0; ni < 4; ++ni) {
        int row = wn * 64 + ni * 16 + (l & 15);
        bf[ni] = *(const short8*)(lb + row * 64 + csw);
      }
#pragma unroll
      for (int mi = 0; mi < 4; ++mi)
#pragma unroll
        for (int ni = 0; ni < 4; ++ni)
          acc[mi][ni] = MFMA_BF16(af[mi], bf[ni], acc[mi][ni]);
    }
    __syncthreads();
  }

  // epilogue: C/D layout col=lane&15, row=(lane>>4)*4+reg (HW-verified)
#pragma unroll
  for (int ni = 0; ni < 4; ++ni) {
    int col = n0 + wn * 64 + ni * 16 + (l & 15);
    float bv = bias[col];
#pragma unroll
    for (int mi = 0; mi < 4; ++mi) {
#pragma unroll
      for (int r = 0; r < 4; ++r) {
        int row = m0 + wm * 64 + mi * 16 + (l >> 4) * 4 + r;
        C[(size_t)row * 4096 + col] = f2bf(acc[mi][ni][r] + bv);
      }
    }
  }
}

// ---------------- persistent recurrent kernel ----------------
// 256 blocks (1/CU, forced by LDS), 256 threads (4 waves).
// Block owns 4 h-indices: hbase..hbase+3 -> 16 gate rows per layer {g*1024+hbase+j}.
// LDS: Wh0/Wi1/Wh1 slices in fragment order (96KB) + gate scratch (6KB).
// Pipeline skew: iteration i computes layer0(t=i) and layer1(t=i-1); one grid barrier/iter.
__launch_bounds__(256, 1)
__global__ void lstm_kernel(const u16* __restrict__ wbf, const float* __restrict__ b1v,
                            const u16* __restrict__ X0,
                            u16* __restrict__ h0buf, u16* __restrict__ h1buf,
                            float* __restrict__ h1f, u32* __restrict__ bar) {
  extern __shared__ char smem[];
  u16* wlds = (u16*)smem;                          // 3 * 16384 u16 = 98304 B
  float* gates0 = (float*)(smem + 98304);          // [32][16]  Wh0.h0 partial
  float* part1  = (float*)(smem + 98304 + 2048);   // [32][16]  Wi1.h0 partial
  float* wh1p   = (float*)(smem + 98304 + 4096);   // [32][16]  Wh1.h1 partial
  u32* flags = bar;                                 // [256]
  u32* gen   = bar + 256;                           // separate cache line

  const int tid = threadIdx.x;
  const int l = tid & 63, w = tid >> 6;
  const int blk = blockIdx.x;
  const int hbase = blk * 4;

  // ---- fill weight LDS in MFMA fragment order: slot(kk,lane,j) = W[row(lane&15)][kk*32+(lane>>4)*8+j]
  for (int m = 0; m < 3; ++m) {
    const u16* Wm = wbf + (size_t)(m + 1) * (4096 * 1024);   // mats: 1=Wh0, 2=Wi1, 3=Wh1
    for (int s = tid; s < 2048; s += 256) {
      int kk = s >> 6, ll = s & 63;
      int nl = ll & 15, hi = ll >> 4;
      int gr = (nl >> 2) * 1024 + hbase + (nl & 3);          // nl = gate*4 + j
      short8 v = *(const short8*)(Wm + (size_t)gr * 1024 + kk * 32 + hi * 8);
      *(short8*)(wlds + m * 16384 + kk * 512 + ll * 8) = v;
    }
  }
  __syncthreads();

  float cst = 0.f;                                 // threads 0..127: c0; 128..255: c1
  const int at = tid & 127, ab = at >> 2, aj = at & 3;
  const int mt = w & 1;                            // batch half (rows mt*16..mt*16+15)

  for (int i = 0; i <= 512; ++i) {
    const int rp = (i + 1) & 1, wp = i & 1;
    f32x4 acc0 = {0.f, 0.f, 0.f, 0.f};
    f32x4 acc1 = {0.f, 0.f, 0.f, 0.f};
    const u16* hr = ((w < 2) ? h0buf : h1buf) + rp * 32768;
    const u16* abase = hr + (mt * 16 + (l & 15)) * 1024 + ((l >> 4) * 8);

    if (w < 2) {   // waves 0,1: A = h0 -> Wh0.h0 (layer0) and Wi1.h0 (layer1 partial)
#pragma unroll 8
      for (int kk = 0; kk < 32; ++kk) {
        short8 a  = *(const short8*)(abase + kk * 32);
        short8 bh = *(const short8*)(wlds + kk * 512 + l * 8);
        acc0 = MFMA_BF16(a, bh, acc0);
        short8 bi = *(const short8*)(wlds + 16384 + kk * 512 + l * 8);
        acc1 = MFMA_BF16(a, bi, acc1);
      }
#pragma unroll
      for (int r = 0; r < 4; ++r) {
        int row = mt * 16 + (l >> 4) * 4 + r, col = l & 15;
        gates0[row * 16 + col] = acc0[r];
        part1[row * 16 + col]  = acc1[r];
      }
    } else {       // waves 2,3: A = h1 -> Wh1.h1 (layer1 partial)
#pragma unroll 8
      for (int kk = 0; kk < 32; ++kk) {
        short8 a  = *(const short8*)(abase + kk * 32);
        short8 bw = *(const short8*)(wlds + 2 * 16384 + kk * 512 + l * 8);
        acc0 = MFMA_BF16(a, bw, acc0);
      }
#pragma unroll
      for (int r = 0; r < 4; ++r) {
        int row = mt * 16 + (l >> 4) * 4 + r, col = l & 15;
        wh1p[row * 16 + col] = acc0[r];
      }
    }
    __syncthreads();

    // ---- activations (gate order i,f,g,o; cols nl = g*4 + j)
    if (tid < 128) {
      if (i < 512) {          // layer0, t = i
        const u16* xp = X0 + (size_t)(i * 32 + ab) * 4096 + hbase + aj;
        float gi = gates0[ab * 16 + aj]      + bf2f(xp[0]);
        float gf = gates0[ab * 16 + 4 + aj]  + bf2f(xp[1024]);
        float gg = gates0[ab * 16 + 8 + aj]  + bf2f(xp[2048]);
        float go = gates0[ab * 16 + 12 + aj] + bf2f(xp[3072]);
        cst = sigm(gf) * cst + sigm(gi) * tanhf(gg);
        float h = sigm(go) * tanhf(cst);
        h0buf[wp * 32768 + ab * 1024 + hbase + aj] = f2bf(h);
      }
    } else {
      if (i >= 1) {           // layer1, t = i-1
        float gi = part1[ab * 16 + aj]      + wh1p[ab * 16 + aj]      + b1v[hbase + aj];
        float gf = part1[ab * 16 + 4 + aj]  + wh1p[ab * 16 + 4 + aj]  + b1v[1024 + hbase + aj];
        float gg = part1[ab * 16 + 8 + aj]  + wh1p[ab * 16 + 8 + aj]  + b1v[2048 + hbase + aj];
        float go = part1[ab * 16 + 12 + aj] + wh1p[ab * 16 + 12 + aj] + b1v[3072 + hbase + aj];
        cst = sigm(gf) * cst + sigm(gi) * tanhf(gg);
        float h = sigm(go) * tanhf(cst);
        h1buf[wp * 32768 + ab * 1024 + hbase + aj] = f2bf(h);
        if (i == 512) h1f[ab * 1024 + hbase + aj] = h;
      }
    }

    // ---- grid barrier (flag-array + generation; monotonic targets, no reset races)
    __syncthreads();
    const u32 target = (u32)(i + 1);
    if (blk == 0) {
      if (tid >= 1 && tid < 256) {
        while (__hip_atomic_load(&flags[tid], __ATOMIC_ACQUIRE, __HIP_MEMORY_SCOPE_AGENT) < target)
          __builtin_amdgcn_s_sleep(2);
      }
      __syncthreads();
      if (tid == 0) {
        __threadfence();
        __hip_atomic_store(gen, target, __ATOMIC_RELEASE, __HIP_MEMORY_SCOPE_AGENT);
      }
      __syncthreads();
    } else {
      if (tid == 0) {
        __threadfence();
        __hip_atomic_store(&flags[blk], target, __ATOMIC_RELEASE, __HIP_MEMORY_SCOPE_AGENT);
        while (__hip_atomic_load(gen, __ATOMIC_ACQUIRE, __HIP_MEMORY_SCOPE_AGENT) < target)
          __builtin_amdgcn_s_sleep(2);
      }
      __syncthreads();
    }
    __threadfence();
  }
}

// ---------------- final FC: out[b][v] = h1f[b,:] . fcw[v,:] + fcb[v] (fp32) ----------------
__global__ void fc_kernel(const float* __restrict__ h1f, const float* __restrict__ fcw,
                          const float* __restrict__ fcb, float* __restrict__ out) {
  int gid = blockIdx.x * 256 + threadIdx.x;
  int v = gid >> 5, b = gid & 31;    // lanes 0..31 share v (broadcast fcw), cover all b
  const float4* wr = (const float4*)(fcw + (size_t)v * 1024);
  const float4* hr = (const float4*)(h1f + (size_t)b * 1024);
  float s = 0.f;
#pragma unroll 8
  for (int i = 0; i < 256; ++i) {
    float4 wv = wr[i], hv = hr[i];
    s += wv.x * hv.x + wv.y * hv.y + wv.z * hv.z + wv.w * hv.w;
  }
  out[(size_t)b * 32000 + v] = s + fcb[v];
}

// ---------------- host launch ----------------
extern "C" void kernel_launch(void* const* d_in, const int* in_sizes, int n_in,
                              void* d_out, int out_size, void* d_ws, size_t ws_size,
                              hipStream_t stream) {
  const int*   x   = (const int*)d_in[0];
  const float* emb = (const float*)d_in[1];
  const float* Wi0 = (const float*)d_in[2];
  const float* bi0 = (const float*)d_in[3];
  const float* Wh0 = (const float*)d_in[4];
  const float* bh0 = (const float*)d_in[5];
  const float* Wi1 = (const float*)d_in[6];
  const float* bi1 = (const float*)d_in[7];
  const float* Wh1 = (const float*)d_in[8];
  const float* bh1 = (const float*)d_in[9];
  const float* fcw = (const float*)d_in[10];
  const float* fcb = (const float*)d_in[11];
  float* out = (float*)d_out;
  char* ws = (char*)d_ws;

  if (ws_size < WS_NEED) return;   // loud failure (validation will catch), no corruption

  u16*   wbf = (u16*)(ws + OFF_W);
  float* b0v = (float*)(ws + OFF_B0);
  float* b1v = (float*)(ws + OFF_B1);
  u16*   h0b = (u16*)(ws + OFF_H0);
  u16*   h1b = (u16*)(ws + OFF_H1);
  float* h1f = (float*)(ws + OFF_H1F);
  u32*   bar = (u32*)(ws + OFF_BAR);
  u16*   xe  = (u16*)(ws + OFF_XE);
  u16*   X0p = (u16*)(ws + OFF_X0);

  // zero h double-buffers, h1f, barrier state — every call (replays must be identical)
  hipMemsetAsync(ws + OFF_H0, 0, OFF_XE - OFF_H0, stream);

  prep_w_kernel<<<16384, 256, 0, stream>>>(Wi0, Wh0, Wi1, Wh1, wbf);
  prep_b_kernel<<<16, 256, 0, stream>>>(bi0, bh0, bi1, bh1, b0v, b1v);
  embed_kernel<<<16384, 256, 0, stream>>>(x, emb, xe);
  x0_gemm_kernel<<<dim3(32, 128), 256, 0, stream>>>(xe, wbf, b0v, X0p);

  hipFuncSetAttribute((const void*)lstm_kernel,
                      hipFuncAttributeMaxDynamicSharedMemorySize, 104448);
  lstm_kernel<<<256, 256, 104448, stream>>>(wbf, b1v, X0p, h0b, h1b, h1f, bar);

  fc_kernel<<<4000, 256, 0, stream>>>(h1f, fcw, fcb, out);
}

// Round 2
// 11136.238 us; speedup vs baseline: 2.3548x; 2.3548x over previous
//
#include <hip/hip_runtime.h>
#include <hip/hip_bf16.h>

typedef __attribute__((ext_vector_type(8))) short short8;
typedef __attribute__((ext_vector_type(4))) float f32x4;
typedef unsigned short u16;
typedef unsigned int u32;

#define MFMA_BF16(a, b, c) __builtin_amdgcn_mfma_f32_16x16x32_bf16((a), (b), (c), 0, 0, 0)

// ---------------- workspace layout (bytes) ----------------
static constexpr size_t OFF_W   = 0;                       // 4 x [4096][1024] bf16 = 32MB (Wi0,Wh0,Wi1,Wh1)
static constexpr size_t OFF_B0  = 33554432;                // 4096 f32 (bi0+bh0)
static constexpr size_t OFF_B1  = OFF_B0 + 16384;          // 4096 f32 (bi1+bh1)
static constexpr size_t OFF_H0  = OFF_B1 + 16384;          // 2 x [32][1024] bf16 (double buffer)
static constexpr size_t OFF_H1  = OFF_H0 + 131072;         // 2 x [32][1024] bf16
static constexpr size_t OFF_H1F = OFF_H1 + 131072;         // [32][1024] f32 (final h1)
static constexpr size_t OFF_XE  = OFF_H1F + 131072;        // [16384][1024] bf16 = 32MB
static constexpr size_t OFF_X0  = OFF_XE + 33554432;       // [16384][4096] bf16 = 128MB
static constexpr size_t WS_NEED = OFF_X0 + 134217728;      // ~192.5 MB
// barrier flags: 256 x 128B = 32KB, overlaid on the TAIL of xe (dead after x0_gemm)
static constexpr size_t OFF_FLG = OFF_X0 - 32768;

// ---------------- helpers ----------------
__device__ __forceinline__ u16 f2bf(float f) {
  u32 x = __builtin_bit_cast(u32, f);
  x += 0x7fffu + ((x >> 16) & 1u);   // RNE (inputs are finite)
  return (u16)(x >> 16);
}
__device__ __forceinline__ float bf2f(u16 u) {
  return __builtin_bit_cast(float, (u32)u << 16);
}
__device__ __forceinline__ float sigm(float x) { return 1.f / (1.f + expf(-x)); }

__device__ __forceinline__ void gload_lds16(const u16* gsrc, u16* ldst) {
  __builtin_amdgcn_global_load_lds(
      (__attribute__((address_space(1))) void*)(u16*)gsrc,
      (__attribute__((address_space(3))) void*)ldst, 16, 0, 0);
}

// ---------------- prep: fp32 weights -> bf16 ----------------
__global__ void prep_w_kernel(const float* __restrict__ Wi0, const float* __restrict__ Wh0,
                              const float* __restrict__ Wi1, const float* __restrict__ Wh1,
                              u16* __restrict__ dst) {
  size_t e = ((size_t)blockIdx.x * 256 + threadIdx.x) * 4;   // 16M elements total
  int mat = (int)(e >> 22);
  size_t off = e & ((1ull << 22) - 1);
  const float* src = (mat == 0) ? Wi0 : (mat == 1) ? Wh0 : (mat == 2) ? Wi1 : Wh1;
  float4 v = *(const float4*)(src + off);
  ushort4 o;
  o.x = f2bf(v.x); o.y = f2bf(v.y); o.z = f2bf(v.z); o.w = f2bf(v.w);
  *(ushort4*)(dst + e) = o;
}

__global__ void prep_b_kernel(const float* __restrict__ bi0, const float* __restrict__ bh0,
                              const float* __restrict__ bi1, const float* __restrict__ bh1,
                              float* __restrict__ b0, float* __restrict__ b1) {
  int i = blockIdx.x * 256 + threadIdx.x;   // 4096
  b0[i] = bi0[i] + bh0[i];
  b1[i] = bi1[i] + bh1[i];
}

// ---------------- embedding gather: xe[t*32+b][e] = emb[x[b][t]][e] (bf16) ----------------
__global__ void embed_kernel(const int* __restrict__ x, const float* __restrict__ emb,
                             u16* __restrict__ xe) {
  int m = blockIdx.x;            // m = t*32 + b
  int b = m & 31, t = m >> 5;
  int id = x[b * 512 + t];
  float4 v = ((const float4*)(emb + (size_t)id * 1024))[threadIdx.x];
  ushort4 o;
  o.x = f2bf(v.x); o.y = f2bf(v.y); o.z = f2bf(v.z); o.w = f2bf(v.w);
  *(ushort4*)(xe + (size_t)m * 1024 + threadIdx.x * 4) = o;
}

// ---------------- X0 GEMM: [16384,1024] x [4096,1024]^T -> bf16 [16384][4096] (+bias) ----------------
__global__ void x0_gemm_kernel(const u16* __restrict__ A, const u16* __restrict__ W,
                               const float* __restrict__ bias, u16* __restrict__ C) {
  __shared__ u16 lds[2][2][8192];   // [buf][A/B][128 rows x 64 cols]
  const int tid = threadIdx.x, l = tid & 63, w = tid >> 6;
  const int n0 = blockIdx.x * 128, m0 = blockIdx.y * 128;
  const int wm = w >> 1, wn = w & 1;
  const int row8 = l >> 3, u = l & 7;

  f32x4 acc[4][4];
#pragma unroll
  for (int a1 = 0; a1 < 4; ++a1)
#pragma unroll
    for (int a2 = 0; a2 < 4; ++a2) acc[a1][a2] = (f32x4){0.f, 0.f, 0.f, 0.f};

  auto stage = [&](int buf, int kt) {
    const int k0 = kt * 64;
#pragma unroll
    for (int q = 0; q < 4; ++q) {
      const int ld = w * 4 + q;
      const int row = ld * 8 + row8;
      const int sw = (u ^ (row & 7)) * 8;
      gload_lds16(A + (size_t)(m0 + row) * 1024 + k0 + sw, &lds[buf][0][ld * 512]);
      gload_lds16(W + (size_t)(n0 + row) * 1024 + k0 + sw, &lds[buf][1][ld * 512]);
    }
  };

  stage(0, 0);
  __syncthreads();

  for (int kt = 0; kt < 16; ++kt) {
    const int buf = kt & 1;
    if (kt < 15) stage(buf ^ 1, kt + 1);
    const u16* la = lds[buf][0];
    const u16* lb = lds[buf][1];
#pragma unroll
    for (int kk = 0; kk < 2; ++kk) {
      const int c = kk * 4 + (l >> 4);
      const int csw = (c ^ (l & 7)) * 8;    // row&7 == l&7 for all frag rows
      short8 af[4], bf[4];
#pragma unroll
      for (int mi = 0; mi < 4; ++mi) {
        int row = wm * 64 + mi * 16 + (l & 15);
        af[mi] = *(const short8*)(la + row * 64 + csw);
      }
#pragma unroll
      for (int ni = 0; ni < 4; ++ni) {
        int row = wn * 64 + ni * 16 + (l & 15);
        bf[ni] = *(const short8*)(lb + row * 64 + csw);
      }
#pragma unroll
      for (int mi = 0; mi < 4; ++mi)
#pragma unroll
        for (int ni = 0; ni < 4; ++ni)
          acc[mi][ni] = MFMA_BF16(af[mi], bf[ni], acc[mi][ni]);
    }
    __syncthreads();
  }

  // epilogue: C/D layout col=lane&15, row=(lane>>4)*4+reg (HW-verified)
#pragma unroll
  for (int ni = 0; ni < 4; ++ni) {
    int col = n0 + wn * 64 + ni * 16 + (l & 15);
    float bv = bias[col];
#pragma unroll
    for (int mi = 0; mi < 4; ++mi) {
#pragma unroll
      for (int r = 0; r < 4; ++r) {
        int row = m0 + wm * 64 + mi * 16 + (l >> 4) * 4 + r;
        C[(size_t)row * 4096 + col] = f2bf(acc[mi][ni][r] + bv);
      }
    }
  }
}

// ---------------- persistent recurrent kernel ----------------
// 256 blocks (1/CU), 256 threads (4 waves). Pipeline skew: iter i = layer0(t=i) + layer1(t=i-1).
// One-hop grid barrier: per-block flag on its OWN 128B line (no line sharing between writers);
// all 256 threads poll one flag each (relaxed), single agent-acquire fence per iteration.
__launch_bounds__(256, 1)
__global__ void lstm_kernel(const u16* __restrict__ wbf, const float* __restrict__ b1v,
                            const u16* __restrict__ X0,
                            u16* __restrict__ h0buf, u16* __restrict__ h1buf,
                            float* __restrict__ h1f, u32* __restrict__ flags) {
  extern __shared__ char smem[];
  u16* wlds = (u16*)smem;                          // 3 * 16384 u16 = 98304 B
  float* gates0 = (float*)(smem + 98304);          // [32][16]  Wh0.h0 partial
  float* part1  = (float*)(smem + 98304 + 2048);   // [32][16]  Wi1.h0 partial
  float* wh1p   = (float*)(smem + 98304 + 4096);   // [32][16]  Wh1.h1 partial

  const int tid = threadIdx.x;
  const int l = tid & 63, w = tid >> 6;
  const int blk = blockIdx.x;
  const int hbase = blk * 4;

  // ---- fill weight LDS in MFMA fragment order: slot(kk,lane,j) = W[row(lane&15)][kk*32+(lane>>4)*8+j]
  for (int m = 0; m < 3; ++m) {
    const u16* Wm = wbf + (size_t)(m + 1) * (4096 * 1024);   // mats: 1=Wh0, 2=Wi1, 3=Wh1
    for (int s = tid; s < 2048; s += 256) {
      int kk = s >> 6, ll = s & 63;
      int nl = ll & 15, hi = ll >> 4;
      int gr = (nl >> 2) * 1024 + hbase + (nl & 3);          // nl = gate*4 + j
      short8 v = *(const short8*)(Wm + (size_t)gr * 1024 + kk * 32 + hi * 8);
      *(short8*)(wlds + m * 16384 + kk * 512 + ll * 8) = v;
    }
  }
  __syncthreads();

  float cst = 0.f;                                 // threads 0..127: c0; 128..255: c1
  const int at = tid & 127, ab = at >> 2, aj = at & 3;
  const int mt = w & 1;                            // batch half (rows mt*16..mt*16+15)

  // loop-invariant layer-1 biases (threads 128..255)
  float b1i = 0.f, b1f = 0.f, b1g = 0.f, b1o = 0.f;
  if (tid >= 128) {
    b1i = b1v[hbase + aj];
    b1f = b1v[1024 + hbase + aj];
    b1g = b1v[2048 + hbase + aj];
    b1o = b1v[3072 + hbase + aj];
  }

  // each thread polls one flag line
  const u32* myflag = flags + (size_t)tid * 32;
  u32* ownflag = flags + (size_t)blk * 32;

  for (int i = 0; i <= 512; ++i) {
    const int rp = (i + 1) & 1, wp = i & 1;

    // early-issue X0 gate loads (fly under the MFMA phase)
    float xg0 = 0.f, xg1 = 0.f, xg2 = 0.f, xg3 = 0.f;
    if (tid < 128 && i < 512) {
      const u16* xp = X0 + (size_t)(i * 32 + ab) * 4096 + hbase + aj;
      xg0 = bf2f(xp[0]); xg1 = bf2f(xp[1024]); xg2 = bf2f(xp[2048]); xg3 = bf2f(xp[3072]);
    }

    f32x4 acc0 = {0.f, 0.f, 0.f, 0.f};
    f32x4 acc1 = {0.f, 0.f, 0.f, 0.f};
    const u16* hr = ((w < 2) ? h0buf : h1buf) + rp * 32768;
    const u16* abase = hr + (mt * 16 + (l & 15)) * 1024 + ((l >> 4) * 8);

    if (w < 2) {   // waves 0,1: A = h0 -> Wh0.h0 (layer0) and Wi1.h0 (layer1 partial)
#pragma unroll 8
      for (int kk = 0; kk < 32; ++kk) {
        short8 a  = *(const short8*)(abase + kk * 32);
        short8 bh = *(const short8*)(wlds + kk * 512 + l * 8);
        acc0 = MFMA_BF16(a, bh, acc0);
        short8 bi = *(const short8*)(wlds + 16384 + kk * 512 + l * 8);
        acc1 = MFMA_BF16(a, bi, acc1);
      }
#pragma unroll
      for (int r = 0; r < 4; ++r) {
        int row = mt * 16 + (l >> 4) * 4 + r, col = l & 15;
        gates0[row * 16 + col] = acc0[r];
        part1[row * 16 + col]  = acc1[r];
      }
    } else {       // waves 2,3: A = h1 -> Wh1.h1 (layer1 partial)
#pragma unroll 8
      for (int kk = 0; kk < 32; ++kk) {
        short8 a  = *(const short8*)(abase + kk * 32);
        short8 bw = *(const short8*)(wlds + 2 * 16384 + kk * 512 + l * 8);
        acc0 = MFMA_BF16(a, bw, acc0);
      }
#pragma unroll
      for (int r = 0; r < 4; ++r) {
        int row = mt * 16 + (l >> 4) * 4 + r, col = l & 15;
        wh1p[row * 16 + col] = acc0[r];
      }
    }
    __syncthreads();

    // ---- activations (gate order i,f,g,o; cols nl = g*4 + j)
    if (tid < 128) {
      if (i < 512) {          // layer0, t = i
        float gi = gates0[ab * 16 + aj]      + xg0;
        float gf = gates0[ab * 16 + 4 + aj]  + xg1;
        float gg = gates0[ab * 16 + 8 + aj]  + xg2;
        float go = gates0[ab * 16 + 12 + aj] + xg3;
        cst = sigm(gf) * cst + sigm(gi) * tanhf(gg);
        float h = sigm(go) * tanhf(cst);
        h0buf[wp * 32768 + ab * 1024 + hbase + aj] = f2bf(h);
      }
    } else {
      if (i >= 1) {           // layer1, t = i-1
        float gi = part1[ab * 16 + aj]      + wh1p[ab * 16 + aj]      + b1i;
        float gf = part1[ab * 16 + 4 + aj]  + wh1p[ab * 16 + 4 + aj]  + b1f;
        float gg = part1[ab * 16 + 8 + aj]  + wh1p[ab * 16 + 8 + aj]  + b1g;
        float go = part1[ab * 16 + 12 + aj] + wh1p[ab * 16 + 12 + aj] + b1o;
        cst = sigm(gf) * cst + sigm(gi) * tanhf(gg);
        float h = sigm(go) * tanhf(cst);
        h1buf[wp * 32768 + ab * 1024 + hbase + aj] = f2bf(h);
        if (i == 512) h1f[ab * 1024 + hbase + aj] = h;
      }
    }

    // ---- one-hop grid barrier
    __syncthreads();                                   // all h writes issued & drained
    const u32 target = (u32)(i + 1);
    if (tid == 0)
      __hip_atomic_store(ownflag, target, __ATOMIC_RELEASE, __HIP_MEMORY_SCOPE_AGENT);
    while (__hip_atomic_load(myflag, __ATOMIC_RELAXED, __HIP_MEMORY_SCOPE_AGENT) < target)
      __builtin_amdgcn_s_sleep(1);
    __syncthreads();                                   // everyone observed all flags
    __builtin_amdgcn_fence(__ATOMIC_ACQUIRE, "agent"); // invalidate stale lines before h reads
  }
}

// ---------------- final FC: out[b][v] = h1f[b,:] . fcw[v,:] + fcb[v] (fp32) ----------------
__global__ void fc_kernel(const float* __restrict__ h1f, const float* __restrict__ fcw,
                          const float* __restrict__ fcb, float* __restrict__ out) {
  int gid = blockIdx.x * 256 + threadIdx.x;
  int v = gid >> 5, b = gid & 31;    // lanes 0..31 share v (broadcast fcw), cover all b
  const float4* wr = (const float4*)(fcw + (size_t)v * 1024);
  const float4* hr = (const float4*)(h1f + (size_t)b * 1024);
  float s = 0.f;
#pragma unroll 8
  for (int i = 0; i < 256; ++i) {
    float4 wv = wr[i], hv = hr[i];
    s += wv.x * hv.x + wv.y * hv.y + wv.z * hv.z + wv.w * hv.w;
  }
  out[(size_t)b * 32000 + v] = s + fcb[v];
}

// ---------------- host launch ----------------
extern "C" void kernel_launch(void* const* d_in, const int* in_sizes, int n_in,
                              void* d_out, int out_size, void* d_ws, size_t ws_size,
                              hipStream_t stream) {
  const int*   x   = (const int*)d_in[0];
  const float* emb = (const float*)d_in[1];
  const float* Wi0 = (const float*)d_in[2];
  const float* bi0 = (const float*)d_in[3];
  const float* Wh0 = (const float*)d_in[4];
  const float* bh0 = (const float*)d_in[5];
  const float* Wi1 = (const float*)d_in[6];
  const float* bi1 = (const float*)d_in[7];
  const float* Wh1 = (const float*)d_in[8];
  const float* bh1 = (const float*)d_in[9];
  const float* fcw = (const float*)d_in[10];
  const float* fcb = (const float*)d_in[11];
  float* out = (float*)d_out;
  char* ws = (char*)d_ws;

  if (ws_size < WS_NEED) return;   // loud failure (validation will catch), no corruption

  u16*   wbf = (u16*)(ws + OFF_W);
  float* b0v = (float*)(ws + OFF_B0);
  float* b1v = (float*)(ws + OFF_B1);
  u16*   h0b = (u16*)(ws + OFF_H0);
  u16*   h1b = (u16*)(ws + OFF_H1);
  float* h1f = (float*)(ws + OFF_H1F);
  u16*   xe  = (u16*)(ws + OFF_XE);
  u16*   X0p = (u16*)(ws + OFF_X0);
  u32*   flg = (u32*)(ws + OFF_FLG);

  // zero h double-buffers + h1f every call (replays must be identical)
  hipMemsetAsync(ws + OFF_H0, 0, OFF_XE - OFF_H0, stream);

  prep_w_kernel<<<16384, 256, 0, stream>>>(Wi0, Wh0, Wi1, Wh1, wbf);
  prep_b_kernel<<<16, 256, 0, stream>>>(bi0, bh0, bi1, bh1, b0v, b1v);
  embed_kernel<<<16384, 256, 0, stream>>>(x, emb, xe);
  x0_gemm_kernel<<<dim3(32, 128), 256, 0, stream>>>(xe, wbf, b0v, X0p);

  // xe tail is dead now -> becomes the padded barrier-flag region (zeroed per call)
  hipMemsetAsync(ws + OFF_FLG, 0, 32768, stream);

  hipFuncSetAttribute((const void*)lstm_kernel,
                      hipFuncAttributeMaxDynamicSharedMemorySize, 104448);
  lstm_kernel<<<256, 256, 104448, stream>>>(wbf, b1v, X0p, h0b, h1b, h1f, flg);

  fc_kernel<<<4000, 256, 0, stream>>>(h1f, fcw, fcb, out);
}

// Round 3
// 5839.218 us; speedup vs baseline: 4.4910x; 1.9071x over previous
//
#include <hip/hip_runtime.h>
#include <hip/hip_bf16.h>

typedef __attribute__((ext_vector_type(8))) short short8;
typedef __attribute__((ext_vector_type(4))) float f32x4;
typedef unsigned short u16;
typedef unsigned int u32;
typedef unsigned long long u64;

#define MFMA_BF16(a, b, c) __builtin_amdgcn_mfma_f32_16x16x32_bf16((a), (b), (c), 0, 0, 0)

// ---------------- workspace layout (bytes) ----------------
static constexpr size_t OFF_W   = 0;                       // 4 x [4096][1024] bf16 = 32MB (Wi0,Wh0,Wi1,Wh1)
static constexpr size_t OFF_B0  = 33554432;                // 4096 f32 (bi0+bh0)
static constexpr size_t OFF_B1  = OFF_B0 + 16384;          // 4096 f32 (bi1+bh1)
static constexpr size_t OFF_H0  = OFF_B1 + 16384;          // 2 x [32][1024] bf16 (double buffer)
static constexpr size_t OFF_H1  = OFF_H0 + 131072;         // 2 x [32][1024] bf16
static constexpr size_t OFF_H1F = OFF_H1 + 131072;         // [32][1024] f32 (final h1)
static constexpr size_t OFF_XE  = OFF_H1F + 131072;        // [16384][1024] bf16 = 32MB
static constexpr size_t OFF_X0  = OFF_XE + 33554432;       // [16384][4096] bf16 = 128MB
static constexpr size_t WS_NEED = OFF_X0 + 134217728;      // ~192.5 MB
// barrier flags: 256 x 128B = 32KB, overlaid on the TAIL of xe (dead after x0_gemm)
static constexpr size_t OFF_FLG = OFF_X0 - 32768;

// ---------------- helpers ----------------
__device__ __forceinline__ u16 f2bf(float f) {
  u32 x = __builtin_bit_cast(u32, f);
  x += 0x7fffu + ((x >> 16) & 1u);   // RNE (inputs are finite)
  return (u16)(x >> 16);
}
__device__ __forceinline__ float bf2f(u16 u) {
  return __builtin_bit_cast(float, (u32)u << 16);
}
__device__ __forceinline__ float sigm(float x) { return 1.f / (1.f + expf(-x)); }

// system-scope (sc0 sc1) relaxed ops: coherent at MALL, no L2 writeback/invalidate
__device__ __forceinline__ u64 sysload64(const void* p) {
  return __hip_atomic_load((const u64*)p, __ATOMIC_RELAXED, __HIP_MEMORY_SCOPE_SYSTEM);
}
__device__ __forceinline__ void sysstore64(void* p, u64 v) {
  __hip_atomic_store((u64*)p, v, __ATOMIC_RELAXED, __HIP_MEMORY_SCOPE_SYSTEM);
}

union U16x8 { u64 q[2]; short8 v; };

__device__ __forceinline__ void gload_lds16(const u16* gsrc, u16* ldst) {
  __builtin_amdgcn_global_load_lds(
      (__attribute__((address_space(1))) void*)(u16*)gsrc,
      (__attribute__((address_space(3))) void*)ldst, 16, 0, 0);
}

// ---------------- prep: fp32 weights -> bf16 ----------------
__global__ void prep_w_kernel(const float* __restrict__ Wi0, const float* __restrict__ Wh0,
                              const float* __restrict__ Wi1, const float* __restrict__ Wh1,
                              u16* __restrict__ dst) {
  size_t e = ((size_t)blockIdx.x * 256 + threadIdx.x) * 4;   // 16M elements total
  int mat = (int)(e >> 22);
  size_t off = e & ((1ull << 22) - 1);
  const float* src = (mat == 0) ? Wi0 : (mat == 1) ? Wh0 : (mat == 2) ? Wi1 : Wh1;
  float4 v = *(const float4*)(src + off);
  ushort4 o;
  o.x = f2bf(v.x); o.y = f2bf(v.y); o.z = f2bf(v.z); o.w = f2bf(v.w);
  *(ushort4*)(dst + e) = o;
}

__global__ void prep_b_kernel(const float* __restrict__ bi0, const float* __restrict__ bh0,
                              const float* __restrict__ bi1, const float* __restrict__ bh1,
                              float* __restrict__ b0, float* __restrict__ b1) {
  int i = blockIdx.x * 256 + threadIdx.x;   // 4096
  b0[i] = bi0[i] + bh0[i];
  b1[i] = bi1[i] + bh1[i];
}

// ---------------- embedding gather: xe[t*32+b][e] = emb[x[b][t]][e] (bf16) ----------------
__global__ void embed_kernel(const int* __restrict__ x, const float* __restrict__ emb,
                             u16* __restrict__ xe) {
  int m = blockIdx.x;            // m = t*32 + b
  int b = m & 31, t = m >> 5;
  int id = x[b * 512 + t];
  float4 v = ((const float4*)(emb + (size_t)id * 1024))[threadIdx.x];
  ushort4 o;
  o.x = f2bf(v.x); o.y = f2bf(v.y); o.z = f2bf(v.z); o.w = f2bf(v.w);
  *(ushort4*)(xe + (size_t)m * 1024 + threadIdx.x * 4) = o;
}

// ---------------- X0 GEMM: [16384,1024] x [4096,1024]^T -> bf16 [16384][4096] (+bias) ----------------
__global__ void x0_gemm_kernel(const u16* __restrict__ A, const u16* __restrict__ W,
                               const float* __restrict__ bias, u16* __restrict__ C) {
  __shared__ u16 lds[2][2][8192];   // [buf][A/B][128 rows x 64 cols]
  const int tid = threadIdx.x, l = tid & 63, w = tid >> 6;
  const int n0 = blockIdx.x * 128, m0 = blockIdx.y * 128;
  const int wm = w >> 1, wn = w & 1;
  const int row8 = l >> 3, u = l & 7;

  f32x4 acc[4][4];
#pragma unroll
  for (int a1 = 0; a1 < 4; ++a1)
#pragma unroll
    for (int a2 = 0; a2 < 4; ++a2) acc[a1][a2] = (f32x4){0.f, 0.f, 0.f, 0.f};

  auto stage = [&](int buf, int kt) {
    const int k0 = kt * 64;
#pragma unroll
    for (int q = 0; q < 4; ++q) {
      const int ld = w * 4 + q;
      const int row = ld * 8 + row8;
      const int sw = (u ^ (row & 7)) * 8;
      gload_lds16(A + (size_t)(m0 + row) * 1024 + k0 + sw, &lds[buf][0][ld * 512]);
      gload_lds16(W + (size_t)(n0 + row) * 1024 + k0 + sw, &lds[buf][1][ld * 512]);
    }
  };

  stage(0, 0);
  __syncthreads();

  for (int kt = 0; kt < 16; ++kt) {
    const int buf = kt & 1;
    if (kt < 15) stage(buf ^ 1, kt + 1);
    const u16* la = lds[buf][0];
    const u16* lb = lds[buf][1];
#pragma unroll
    for (int kk = 0; kk < 2; ++kk) {
      const int c = kk * 4 + (l >> 4);
      const int csw = (c ^ (l & 7)) * 8;    // row&7 == l&7 for all frag rows
      short8 af[4], bf[4];
#pragma unroll
      for (int mi = 0; mi < 4; ++mi) {
        int row = wm * 64 + mi * 16 + (l & 15);
        af[mi] = *(const short8*)(la + row * 64 + csw);
      }
#pragma unroll
      for (int ni = 0; ni < 4; ++ni) {
        int row = wn * 64 + ni * 16 + (l & 15);
        bf[ni] = *(const short8*)(lb + row * 64 + csw);
      }
#pragma unroll
      for (int mi = 0; mi < 4; ++mi)
#pragma unroll
        for (int ni = 0; ni < 4; ++ni)
          acc[mi][ni] = MFMA_BF16(af[mi], bf[ni], acc[mi][ni]);
    }
    __syncthreads();
  }

  // epilogue: C/D layout col=lane&15, row=(lane>>4)*4+reg (HW-verified)
#pragma unroll
  for (int ni = 0; ni < 4; ++ni) {
    int col = n0 + wn * 64 + ni * 16 + (l & 15);
    float bv = bias[col];
#pragma unroll
    for (int mi = 0; mi < 4; ++mi) {
#pragma unroll
      for (int r = 0; r < 4; ++r) {
        int row = m0 + wm * 64 + mi * 16 + (l >> 4) * 4 + r;
        C[(size_t)row * 4096 + col] = f2bf(acc[mi][ni][r] + bv);
      }
    }
  }
}

// ---------------- persistent recurrent kernel ----------------
// 256 blocks (1/CU), 256 threads (4 waves). Pipeline skew: iter i = layer0(t=i) + layer1(t=i-1).
// Coherence: h + flags use relaxed SYSTEM-scope (sc0 sc1) accesses only — no buffer_wbl2 /
// buffer_inv per step, so X0 and everything else stays warm in L2 across all 512 steps.
__launch_bounds__(256, 1)
__global__ void lstm_kernel(const u16* __restrict__ wbf, const float* __restrict__ b1v,
                            const u16* __restrict__ X0,
                            u16* __restrict__ h0buf, u16* __restrict__ h1buf,
                            float* __restrict__ h1f, u32* __restrict__ flags) {
  extern __shared__ char smem[];
  u16* wlds = (u16*)smem;                          // 3 * 16384 u16 = 98304 B
  float* gates0 = (float*)(smem + 98304);          // [32][16]  Wh0.h0 partial
  float* part1  = (float*)(smem + 98304 + 2048);   // [32][16]  Wi1.h0 partial
  float* wh1p   = (float*)(smem + 98304 + 4096);   // [32][16]  Wh1.h1 partial

  const int tid = threadIdx.x;
  const int l = tid & 63, w = tid >> 6;
  const int blk = blockIdx.x;
  const int hbase = blk * 4;

  // ---- fill weight LDS in MFMA fragment order: slot(kk,lane,j) = W[row(lane&15)][kk*32+(lane>>4)*8+j]
  for (int m = 0; m < 3; ++m) {
    const u16* Wm = wbf + (size_t)(m + 1) * (4096 * 1024);   // mats: 1=Wh0, 2=Wi1, 3=Wh1
    for (int s = tid; s < 2048; s += 256) {
      int kk = s >> 6, ll = s & 63;
      int nl = ll & 15, hi = ll >> 4;
      int gr = (nl >> 2) * 1024 + hbase + (nl & 3);          // nl = gate*4 + j
      short8 v = *(const short8*)(Wm + (size_t)gr * 1024 + kk * 32 + hi * 8);
      *(short8*)(wlds + m * 16384 + kk * 512 + ll * 8) = v;
    }
  }
  __syncthreads();

  float cst = 0.f;                                 // threads 0..127: c0; 128..255: c1
  const int at = tid & 127, ab = at >> 2, aj = at & 3;
  const int mt = w & 1;                            // batch half (rows mt*16..mt*16+15)

  // loop-invariant layer-1 biases (threads 128..255)
  float b1i = 0.f, b1f = 0.f, b1g = 0.f, b1o = 0.f;
  if (tid >= 128) {
    b1i = b1v[hbase + aj];
    b1f = b1v[1024 + hbase + aj];
    b1g = b1v[2048 + hbase + aj];
    b1o = b1v[3072 + hbase + aj];
  }

  // each thread polls one flag line
  const u32* myflag = flags + (size_t)tid * 32;
  u32* ownflag = flags + (size_t)blk * 32;

  for (int i = 0; i <= 512; ++i) {
    const int rp = (i + 1) & 1, wp = i & 1;

    // early-issue X0 gate loads (normal cached loads; L2 stays warm — no invalidates)
    float xg0 = 0.f, xg1 = 0.f, xg2 = 0.f, xg3 = 0.f;
    if (tid < 128 && i < 512) {
      const u16* xp = X0 + (size_t)(i * 32 + ab) * 4096 + hbase + aj;
      xg0 = bf2f(xp[0]); xg1 = bf2f(xp[1024]); xg2 = bf2f(xp[2048]); xg3 = bf2f(xp[3072]);
    }

    f32x4 acc0 = {0.f, 0.f, 0.f, 0.f};
    f32x4 acc1 = {0.f, 0.f, 0.f, 0.f};
    const u16* hr = ((w < 2) ? h0buf : h1buf) + rp * 32768;
    const u16* abase = hr + (mt * 16 + (l & 15)) * 1024 + ((l >> 4) * 8);

    // preload ALL h fragments (system-scope bypass loads, fully pipelined into registers)
    short8 areg[32];
#pragma unroll
    for (int kk = 0; kk < 32; ++kk) {
      U16x8 u;
      u.q[0] = sysload64(abase + kk * 32);
      u.q[1] = sysload64(abase + kk * 32 + 4);
      areg[kk] = u.v;
    }

    if (w < 2) {   // waves 0,1: A = h0 -> Wh0.h0 (layer0) and Wi1.h0 (layer1 partial)
#pragma unroll
      for (int kk = 0; kk < 32; ++kk) {
        short8 bh = *(const short8*)(wlds + kk * 512 + l * 8);
        acc0 = MFMA_BF16(areg[kk], bh, acc0);
        short8 bi = *(const short8*)(wlds + 16384 + kk * 512 + l * 8);
        acc1 = MFMA_BF16(areg[kk], bi, acc1);
      }
#pragma unroll
      for (int r = 0; r < 4; ++r) {
        int row = mt * 16 + (l >> 4) * 4 + r, col = l & 15;
        gates0[row * 16 + col] = acc0[r];
        part1[row * 16 + col]  = acc1[r];
      }
    } else {       // waves 2,3: A = h1 -> Wh1.h1 (layer1 partial)
#pragma unroll
      for (int kk = 0; kk < 32; ++kk) {
        short8 bw = *(const short8*)(wlds + 2 * 16384 + kk * 512 + l * 8);
        acc0 = MFMA_BF16(areg[kk], bw, acc0);
      }
#pragma unroll
      for (int r = 0; r < 4; ++r) {
        int row = mt * 16 + (l >> 4) * 4 + r, col = l & 15;
        wh1p[row * 16 + col] = acc0[r];
      }
    }
    __syncthreads();

    // ---- activations (gate order i,f,g,o; cols nl = g*4 + j)
    if (tid < 128) {
      if (i < 512) {          // layer0, t = i
        float gi = gates0[ab * 16 + aj]      + xg0;
        float gf = gates0[ab * 16 + 4 + aj]  + xg1;
        float gg = gates0[ab * 16 + 8 + aj]  + xg2;
        float go = gates0[ab * 16 + 12 + aj] + xg3;
        cst = sigm(gf) * cst + sigm(gi) * tanhf(gg);
        float h = sigm(go) * tanhf(cst);
        // pack 4 dims (aj=0..3) into one 8B system store from the aj==0 lane
        u32 hv = (u32)f2bf(h);
        u32 p1 = (u32)__shfl_xor((int)hv, 1);
        u32 lo = (aj & 1) ? ((p1 & 0xffff) | (hv << 16)) : ((hv & 0xffff) | (p1 << 16));
        u32 p2 = (u32)__shfl_xor((int)lo, 2);
        if (aj == 0)
          sysstore64(h0buf + wp * 32768 + ab * 1024 + hbase,
                     (u64)lo | ((u64)p2 << 32));
      }
    } else {
      if (i >= 1) {           // layer1, t = i-1
        float gi = part1[ab * 16 + aj]      + wh1p[ab * 16 + aj]      + b1i;
        float gf = part1[ab * 16 + 4 + aj]  + wh1p[ab * 16 + 4 + aj]  + b1f;
        float gg = part1[ab * 16 + 8 + aj]  + wh1p[ab * 16 + 8 + aj]  + b1g;
        float go = part1[ab * 16 + 12 + aj] + wh1p[ab * 16 + 12 + aj] + b1o;
        cst = sigm(gf) * cst + sigm(gi) * tanhf(gg);
        float h = sigm(go) * tanhf(cst);
        u32 hv = (u32)f2bf(h);
        u32 p1 = (u32)__shfl_xor((int)hv, 1);
        u32 lo = (aj & 1) ? ((p1 & 0xffff) | (hv << 16)) : ((hv & 0xffff) | (p1 << 16));
        u32 p2 = (u32)__shfl_xor((int)lo, 2);
        if (aj == 0)
          sysstore64(h1buf + wp * 32768 + ab * 1024 + hbase,
                     (u64)lo | ((u64)p2 << 32));
        if (i == 512) h1f[ab * 1024 + hbase + aj] = h;   // normal store; kernel-end release
      }
    }

    // ---- one-hop grid barrier (system-scope flags; __syncthreads drains vmcnt first)
    __syncthreads();                                   // all h system-stores completed
    const u32 target = (u32)(i + 1);
    if (tid == 0)
      __hip_atomic_store(ownflag, target, __ATOMIC_RELAXED, __HIP_MEMORY_SCOPE_SYSTEM);
    while (__hip_atomic_load(myflag, __ATOMIC_RELAXED, __HIP_MEMORY_SCOPE_SYSTEM) < target)
      __builtin_amdgcn_s_sleep(1);
    __syncthreads();                                   // everyone observed all flags
  }
}

// ---------------- final FC: out[b][v] = h1f[b,:] . fcw[v,:] + fcb[v] (fp32) ----------------
__global__ void fc_kernel(const float* __restrict__ h1f, const float* __restrict__ fcw,
                          const float* __restrict__ fcb, float* __restrict__ out) {
  int gid = blockIdx.x * 256 + threadIdx.x;
  int v = gid >> 5, b = gid & 31;    // lanes 0..31 share v (broadcast fcw), cover all b
  const float4* wr = (const float4*)(fcw + (size_t)v * 1024);
  const float4* hr = (const float4*)(h1f + (size_t)b * 1024);
  float s = 0.f;
#pragma unroll 8
  for (int i = 0; i < 256; ++i) {
    float4 wv = wr[i], hv = hr[i];
    s += wv.x * hv.x + wv.y * hv.y + wv.z * hv.z + wv.w * hv.w;
  }
  out[(size_t)b * 32000 + v] = s + fcb[v];
}

// ---------------- host launch ----------------
extern "C" void kernel_launch(void* const* d_in, const int* in_sizes, int n_in,
                              void* d_out, int out_size, void* d_ws, size_t ws_size,
                              hipStream_t stream) {
  const int*   x   = (const int*)d_in[0];
  const float* emb = (const float*)d_in[1];
  const float* Wi0 = (const float*)d_in[2];
  const float* bi0 = (const float*)d_in[3];
  const float* Wh0 = (const float*)d_in[4];
  const float* bh0 = (const float*)d_in[5];
  const float* Wi1 = (const float*)d_in[6];
  const float* bi1 = (const float*)d_in[7];
  const float* Wh1 = (const float*)d_in[8];
  const float* bh1 = (const float*)d_in[9];
  const float* fcw = (const float*)d_in[10];
  const float* fcb = (const float*)d_in[11];
  float* out = (float*)d_out;
  char* ws = (char*)d_ws;

  if (ws_size < WS_NEED) return;   // loud failure (validation will catch), no corruption

  u16*   wbf = (u16*)(ws + OFF_W);
  float* b0v = (float*)(ws + OFF_B0);
  float* b1v = (float*)(ws + OFF_B1);
  u16*   h0b = (u16*)(ws + OFF_H0);
  u16*   h1b = (u16*)(ws + OFF_H1);
  float* h1f = (float*)(ws + OFF_H1F);
  u16*   xe  = (u16*)(ws + OFF_XE);
  u16*   X0p = (u16*)(ws + OFF_X0);
  u32*   flg = (u32*)(ws + OFF_FLG);

  // zero h double-buffers + h1f every call (replays must be identical)
  hipMemsetAsync(ws + OFF_H0, 0, OFF_XE - OFF_H0, stream);

  prep_w_kernel<<<16384, 256, 0, stream>>>(Wi0, Wh0, Wi1, Wh1, wbf);
  prep_b_kernel<<<16, 256, 0, stream>>>(bi0, bh0, bi1, bh1, b0v, b1v);
  embed_kernel<<<16384, 256, 0, stream>>>(x, emb, xe);
  x0_gemm_kernel<<<dim3(32, 128), 256, 0, stream>>>(xe, wbf, b0v, X0p);

  // xe tail is dead now -> becomes the padded barrier-flag region (zeroed per call)
  hipMemsetAsync(ws + OFF_FLG, 0, 32768, stream);

  hipFuncSetAttribute((const void*)lstm_kernel,
                      hipFuncAttributeMaxDynamicSharedMemorySize, 104448);
  lstm_kernel<<<256, 256, 104448, stream>>>(wbf, b1v, X0p, h0b, h1b, h1f, flg);

  fc_kernel<<<4000, 256, 0, stream>>>(h1f, fcw, fcb, out);
}

// Round 6
// 4518.016 us; speedup vs baseline: 5.8043x; 1.2924x over previous
//
#include <hip/hip_runtime.h>
#include <hip/hip_bf16.h>

typedef __attribute__((ext_vector_type(8))) short short8;
typedef __attribute__((ext_vector_type(4))) float f32x4;
typedef __attribute__((ext_vector_type(4))) int i32x4;
typedef unsigned short u16;
typedef unsigned int u32;
typedef unsigned long long u64;

#define MFMA_BF16(a, b, c) __builtin_amdgcn_mfma_f32_16x16x32_bf16((a), (b), (c), 0, 0, 0)

// ---------------- workspace layout (bytes) ----------------
static constexpr size_t OFF_W   = 0;                       // 4 x [4096][1024] bf16 = 32MB
static constexpr size_t OFF_B0  = 33554432;                // 4096 f32 (bi0+bh0)
static constexpr size_t OFF_B1  = OFF_B0 + 16384;          // 4096 f32 (bi1+bh1)
static constexpr size_t OFF_H0  = OFF_B1 + 16384;          // 2 x [32][1024] bf16 (double buffer, MALL master)
static constexpr size_t OFF_H1  = OFF_H0 + 131072;         // 2 x [32][1024] bf16
static constexpr size_t OFF_H1F = OFF_H1 + 131072;         // [32][1024] f32 (final h1)
static constexpr size_t OFF_XE  = OFF_H1F + 131072;        // [16384][1024] bf16 = 32MB
static constexpr size_t OFF_X0  = OFF_XE + 33554432;       // [16384][4096] bf16 = 128MB
static constexpr size_t WS_NEED = OFF_X0 + 134217728;      // ~192.5 MB
// barrier flags: 256 x 128B = 32KB, overlaid on the TAIL of xe (dead after x0_gemm)
static constexpr size_t OFF_FLG = OFF_X0 - 32768;

// ---------------- helpers ----------------
__device__ __forceinline__ u16 f2bf(float f) {
  u32 x = __builtin_bit_cast(u32, f);
  x += 0x7fffu + ((x >> 16) & 1u);   // RNE (inputs are finite)
  return (u16)(x >> 16);
}
__device__ __forceinline__ float bf2f(u16 u) {
  return __builtin_bit_cast(float, (u32)u << 16);
}
__device__ __forceinline__ float sigm(float x) { return 1.f / (1.f + expf(-x)); }

// system-scope (MALL-coherent) relaxed ops
__device__ __forceinline__ void sysstore64(void* p, u64 v) {
  __hip_atomic_store((u64*)p, v, __ATOMIC_RELAXED, __HIP_MEMORY_SCOPE_SYSTEM);
}

// 16B system-scope bypass load (sc0 sc1: past L1+L2, served by MALL).
// "=&v" EARLY-CLOBBER is essential: output must not alias the address pair
// (R4 hang root-cause candidate: clobbered base address on loads 2..32).
template <int OFF>
__device__ __forceinline__ i32x4 ld16_sys(const u16* p) {
  i32x4 v;
  asm volatile("global_load_dwordx4 %0, %1, off offset:%2 sc0 sc1"
               : "=&v"(v) : "v"(p), "n"(OFF));
  return v;
}

__device__ __forceinline__ void gload_lds16(const u16* gsrc, u16* ldst) {
  __builtin_amdgcn_global_load_lds(
      (__attribute__((address_space(1))) void*)(u16*)gsrc,
      (__attribute__((address_space(3))) void*)ldst, 16, 0, 0);
}

// ---------------- prep: fp32 weights -> bf16 ----------------
__global__ void prep_w_kernel(const float* __restrict__ Wi0, const float* __restrict__ Wh0,
                              const float* __restrict__ Wi1, const float* __restrict__ Wh1,
                              u16* __restrict__ dst) {
  size_t e = ((size_t)blockIdx.x * 256 + threadIdx.x) * 4;   // 16M elements total
  int mat = (int)(e >> 22);
  size_t off = e & ((1ull << 22) - 1);
  const float* src = (mat == 0) ? Wi0 : (mat == 1) ? Wh0 : (mat == 2) ? Wi1 : Wh1;
  float4 v = *(const float4*)(src + off);
  ushort4 o;
  o.x = f2bf(v.x); o.y = f2bf(v.y); o.z = f2bf(v.z); o.w = f2bf(v.w);
  *(ushort4*)(dst + e) = o;
}

__global__ void prep_b_kernel(const float* __restrict__ bi0, const float* __restrict__ bh0,
                              const float* __restrict__ bi1, const float* __restrict__ bh1,
                              float* __restrict__ b0, float* __restrict__ b1) {
  int i = blockIdx.x * 256 + threadIdx.x;   // 4096
  b0[i] = bi0[i] + bh0[i];
  b1[i] = bi1[i] + bh1[i];
}

// ---------------- embedding gather ----------------
__global__ void embed_kernel(const int* __restrict__ x, const float* __restrict__ emb,
                             u16* __restrict__ xe) {
  int m = blockIdx.x;            // m = t*32 + b
  int b = m & 31, t = m >> 5;
  int id = x[b * 512 + t];
  float4 v = ((const float4*)(emb + (size_t)id * 1024))[threadIdx.x];
  ushort4 o;
  o.x = f2bf(v.x); o.y = f2bf(v.y); o.z = f2bf(v.z); o.w = f2bf(v.w);
  *(ushort4*)(xe + (size_t)m * 1024 + threadIdx.x * 4) = o;
}

// ---------------- X0 GEMM: [16384,1024] x [4096,1024]^T -> bf16 [16384][4096] (+bias) ----------------
__global__ void x0_gemm_kernel(const u16* __restrict__ A, const u16* __restrict__ W,
                               const float* __restrict__ bias, u16* __restrict__ C) {
  __shared__ u16 lds[2][2][8192];   // [buf][A/B][128 rows x 64 cols]
  const int tid = threadIdx.x, l = tid & 63, w = tid >> 6;
  const int n0 = blockIdx.x * 128, m0 = blockIdx.y * 128;
  const int wm = w >> 1, wn = w & 1;
  const int row8 = l >> 3, u = l & 7;

  f32x4 acc[4][4];
#pragma unroll
  for (int a1 = 0; a1 < 4; ++a1)
#pragma unroll
    for (int a2 = 0; a2 < 4; ++a2) acc[a1][a2] = (f32x4){0.f, 0.f, 0.f, 0.f};

  auto stage = [&](int buf, int kt) {
    const int k0 = kt * 64;
#pragma unroll
    for (int q = 0; q < 4; ++q) {
      const int ld = w * 4 + q;
      const int row = ld * 8 + row8;
      const int sw = (u ^ (row & 7)) * 8;
      gload_lds16(A + (size_t)(m0 + row) * 1024 + k0 + sw, &lds[buf][0][ld * 512]);
      gload_lds16(W + (size_t)(n0 + row) * 1024 + k0 + sw, &lds[buf][1][ld * 512]);
    }
  };

  stage(0, 0);
  __syncthreads();

  for (int kt = 0; kt < 16; ++kt) {
    const int buf = kt & 1;
    if (kt < 15) stage(buf ^ 1, kt + 1);
    const u16* la = lds[buf][0];
    const u16* lb = lds[buf][1];
#pragma unroll
    for (int kk = 0; kk < 2; ++kk) {
      const int c = kk * 4 + (l >> 4);
      const int csw = (c ^ (l & 7)) * 8;    // row&7 == l&7 for all frag rows
      short8 af[4], bf[4];
#pragma unroll
      for (int mi = 0; mi < 4; ++mi) {
        int row = wm * 64 + mi * 16 + (l & 15);
        af[mi] = *(const short8*)(la + row * 64 + csw);
      }
#pragma unroll
      for (int ni = 0; ni < 4; ++ni) {
        int row = wn * 64 + ni * 16 + (l & 15);
        bf[ni] = *(const short8*)(lb + row * 64 + csw);
      }
#pragma unroll
      for (int mi = 0; mi < 4; ++mi)
#pragma unroll
        for (int ni = 0; ni < 4; ++ni)
          acc[mi][ni] = MFMA_BF16(af[mi], bf[ni], acc[mi][ni]);
    }
    __syncthreads();
  }

#pragma unroll
  for (int ni = 0; ni < 4; ++ni) {
    int col = n0 + wn * 64 + ni * 16 + (l & 15);
    float bv = bias[col];
#pragma unroll
    for (int mi = 0; mi < 4; ++mi) {
#pragma unroll
      for (int r = 0; r < 4; ++r) {
        int row = m0 + wm * 64 + mi * 16 + (l >> 4) * 4 + r;
        C[(size_t)row * 4096 + col] = f2bf(acc[mi][ni][r] + bv);
      }
    }
  }
}

// ---------------- persistent recurrent kernel ----------------
// 256 blocks (1/CU), 256 threads (4 waves). Iter i = layer0(t=i) + layer1(t=i-1).
// Proven R3 flat barrier (per-block padded system flags, all-poll). h broadcast via
// 16B sc0 sc1 asm loads (half the request count of the R3 8B path).
__launch_bounds__(256, 1)
__global__ void lstm_kernel(const u16* __restrict__ wbf, const float* __restrict__ b1v,
                            const u16* __restrict__ X0,
                            u16* __restrict__ h0buf, u16* __restrict__ h1buf,
                            float* __restrict__ h1f, u32* __restrict__ flags) {
  extern __shared__ char smem[];
  u16* wlds = (u16*)smem;                          // 3 * 16384 u16 = 98304 B
  float* gates0 = (float*)(smem + 98304);          // [32][16]  Wh0.h0
  float* part1  = (float*)(smem + 98304 + 2048);   // [32][16]  Wi1.h0
  float* wh1p   = (float*)(smem + 98304 + 4096);   // [32][16]  Wh1.h1

  const int tid = threadIdx.x;
  const int l = tid & 63, w = tid >> 6;
  const int blk = blockIdx.x;
  const int hbase = blk * 4;

  // ---- fill weight LDS in MFMA fragment order
  for (int m = 0; m < 3; ++m) {
    const u16* Wm = wbf + (size_t)(m + 1) * (4096 * 1024);   // 1=Wh0, 2=Wi1, 3=Wh1
    for (int s = tid; s < 2048; s += 256) {
      int kk = s >> 6, ll = s & 63;
      int nl = ll & 15, hi = ll >> 4;
      int gr = (nl >> 2) * 1024 + hbase + (nl & 3);
      short8 v = *(const short8*)(Wm + (size_t)gr * 1024 + kk * 32 + hi * 8);
      *(short8*)(wlds + m * 16384 + kk * 512 + ll * 8) = v;
    }
  }
  __syncthreads();

  float cst = 0.f;                                 // threads 0..127: c0; 128..255: c1
  const int at = tid & 127, ab = at >> 2, aj = at & 3;
  const int mt = w & 1;

  float b1i = 0.f, b1fv = 0.f, b1g = 0.f, b1o = 0.f;
  if (tid >= 128) {
    b1i  = b1v[hbase + aj];
    b1fv = b1v[1024 + hbase + aj];
    b1g  = b1v[2048 + hbase + aj];
    b1o  = b1v[3072 + hbase + aj];
  }

  const u32* myflag = flags + (size_t)tid * 32;
  u32* ownflag = flags + (size_t)blk * 32;

  for (int i = 0; i <= 512; ++i) {
    const int rp = (i + 1) & 1, wp = i & 1;

    // early X0 gate loads (normal cached; L2 stays warm — no cache-wide fences anywhere)
    float xg0 = 0.f, xg1 = 0.f, xg2 = 0.f, xg3 = 0.f;
    if (tid < 128 && i < 512) {
      const u16* xp = X0 + (size_t)(i * 32 + ab) * 4096 + hbase + aj;
      xg0 = bf2f(xp[0]); xg1 = bf2f(xp[1024]); xg2 = bf2f(xp[2048]); xg3 = bf2f(xp[3072]);
    }

    // ---- preload ALL h fragments: 32 x 16B system-bypass loads, fully pipelined
    const u16* hr = ((w < 2) ? h0buf : h1buf) + rp * 32768;
    const u16* abase = hr + (mt * 16 + (l & 15)) * 1024 + ((l >> 4) * 8);
    i32x4 ar[32];
#define P(k) ar[k] = ld16_sys<(k) * 64>(abase)
    P(0);P(1);P(2);P(3);P(4);P(5);P(6);P(7);
    P(8);P(9);P(10);P(11);P(12);P(13);P(14);P(15);
    P(16);P(17);P(18);P(19);P(20);P(21);P(22);P(23);
    P(24);P(25);P(26);P(27);P(28);P(29);P(30);P(31);
#undef P
    asm volatile("s_waitcnt vmcnt(0)" ::: "memory");
    __builtin_amdgcn_sched_barrier(0);

    if (w < 2) {   // waves 0,1: Wh0.h0 and Wi1.h0 (two independent chains each)
      f32x4 a0a = {0,0,0,0}, a0b = {0,0,0,0}, a1a = {0,0,0,0}, a1b = {0,0,0,0};
#pragma unroll
      for (int kk = 0; kk < 16; ++kk) {
        short8 e0 = __builtin_bit_cast(short8, ar[2 * kk]);
        short8 e1 = __builtin_bit_cast(short8, ar[2 * kk + 1]);
        a0a = MFMA_BF16(e0, *(const short8*)(wlds + (2 * kk) * 512 + l * 8), a0a);
        a1a = MFMA_BF16(e0, *(const short8*)(wlds + 16384 + (2 * kk) * 512 + l * 8), a1a);
        a0b = MFMA_BF16(e1, *(const short8*)(wlds + (2 * kk + 1) * 512 + l * 8), a0b);
        a1b = MFMA_BF16(e1, *(const short8*)(wlds + 16384 + (2 * kk + 1) * 512 + l * 8), a1b);
      }
#pragma unroll
      for (int r = 0; r < 4; ++r) {
        int row = mt * 16 + (l >> 4) * 4 + r, col = l & 15;
        gates0[row * 16 + col] = a0a[r] + a0b[r];
        part1[row * 16 + col]  = a1a[r] + a1b[r];
      }
    } else {       // waves 2,3: Wh1.h1
      f32x4 a0a = {0,0,0,0}, a0b = {0,0,0,0};
#pragma unroll
      for (int kk = 0; kk < 16; ++kk) {
        short8 e0 = __builtin_bit_cast(short8, ar[2 * kk]);
        short8 e1 = __builtin_bit_cast(short8, ar[2 * kk + 1]);
        a0a = MFMA_BF16(e0, *(const short8*)(wlds + 2 * 16384 + (2 * kk) * 512 + l * 8), a0a);
        a0b = MFMA_BF16(e1, *(const short8*)(wlds + 2 * 16384 + (2 * kk + 1) * 512 + l * 8), a0b);
      }
#pragma unroll
      for (int r = 0; r < 4; ++r) {
        int row = mt * 16 + (l >> 4) * 4 + r, col = l & 15;
        wh1p[row * 16 + col] = a0a[r] + a0b[r];
      }
    }
    __syncthreads();

    // ---- activations + h system-store (packed 8B per 4 dims)
    if (tid < 128) {
      if (i < 512) {
        float gi = gates0[ab * 16 + aj]      + xg0;
        float gf = gates0[ab * 16 + 4 + aj]  + xg1;
        float gg = gates0[ab * 16 + 8 + aj]  + xg2;
        float go = gates0[ab * 16 + 12 + aj] + xg3;
        cst = sigm(gf) * cst + sigm(gi) * tanhf(gg);
        float h = sigm(go) * tanhf(cst);
        u32 hv = (u32)f2bf(h);
        u32 p1 = (u32)__shfl_xor((int)hv, 1);
        u32 lo = (aj & 1) ? ((p1 & 0xffff) | (hv << 16)) : ((hv & 0xffff) | (p1 << 16));
        u32 p2 = (u32)__shfl_xor((int)lo, 2);
        if (aj == 0)
          sysstore64(h0buf + wp * 32768 + ab * 1024 + hbase, (u64)lo | ((u64)p2 << 32));
      }
    } else {
      if (i >= 1) {
        float gi = part1[ab * 16 + aj]      + wh1p[ab * 16 + aj]      + b1i;
        float gf = part1[ab * 16 + 4 + aj]  + wh1p[ab * 16 + 4 + aj]  + b1fv;
        float gg = part1[ab * 16 + 8 + aj]  + wh1p[ab * 16 + 8 + aj]  + b1g;
        float go = part1[ab * 16 + 12 + aj] + wh1p[ab * 16 + 12 + aj] + b1o;
        cst = sigm(gf) * cst + sigm(gi) * tanhf(gg);
        float h = sigm(go) * tanhf(cst);
        u32 hv = (u32)f2bf(h);
        u32 p1 = (u32)__shfl_xor((int)hv, 1);
        u32 lo = (aj & 1) ? ((p1 & 0xffff) | (hv << 16)) : ((hv & 0xffff) | (p1 << 16));
        u32 p2 = (u32)__shfl_xor((int)lo, 2);
        if (aj == 0)
          sysstore64(h1buf + wp * 32768 + ab * 1024 + hbase, (u64)lo | ((u64)p2 << 32));
        if (i == 512) h1f[ab * 1024 + hbase + aj] = h;
      }
    }

    // ---- flat one-hop grid barrier (proven in R2/R3)
    __syncthreads();                                   // all h system-stores drained
    const u32 target = (u32)(i + 1);
    if (tid == 0)
      __hip_atomic_store(ownflag, target, __ATOMIC_RELAXED, __HIP_MEMORY_SCOPE_SYSTEM);
    while (__hip_atomic_load(myflag, __ATOMIC_RELAXED, __HIP_MEMORY_SCOPE_SYSTEM) < target)
      __builtin_amdgcn_s_sleep(1);
    __syncthreads();                                   // everyone observed all flags
  }
}

// ---------------- final FC ----------------
__global__ void fc_kernel(const float* __restrict__ h1f, const float* __restrict__ fcw,
                          const float* __restrict__ fcb, float* __restrict__ out) {
  int gid = blockIdx.x * 256 + threadIdx.x;
  int v = gid >> 5, b = gid & 31;
  const float4* wr = (const float4*)(fcw + (size_t)v * 1024);
  const float4* hr = (const float4*)(h1f + (size_t)b * 1024);
  float s = 0.f;
#pragma unroll 8
  for (int i = 0; i < 256; ++i) {
    float4 wv = wr[i], hv = hr[i];
    s += wv.x * hv.x + wv.y * hv.y + wv.z * hv.z + wv.w * hv.w;
  }
  out[(size_t)b * 32000 + v] = s + fcb[v];
}

// ---------------- host launch ----------------
extern "C" void kernel_launch(void* const* d_in, const int* in_sizes, int n_in,
                              void* d_out, int out_size, void* d_ws, size_t ws_size,
                              hipStream_t stream) {
  const int*   x   = (const int*)d_in[0];
  const float* emb = (const float*)d_in[1];
  const float* Wi0 = (const float*)d_in[2];
  const float* bi0 = (const float*)d_in[3];
  const float* Wh0 = (const float*)d_in[4];
  const float* bh0 = (const float*)d_in[5];
  const float* Wi1 = (const float*)d_in[6];
  const float* bi1 = (const float*)d_in[7];
  const float* Wh1 = (const float*)d_in[8];
  const float* bh1 = (const float*)d_in[9];
  const float* fcw = (const float*)d_in[10];
  const float* fcb = (const float*)d_in[11];
  float* out = (float*)d_out;
  char* ws = (char*)d_ws;

  if (ws_size < WS_NEED) return;

  u16*   wbf = (u16*)(ws + OFF_W);
  float* b0v = (float*)(ws + OFF_B0);
  float* b1v = (float*)(ws + OFF_B1);
  u16*   h0b = (u16*)(ws + OFF_H0);
  u16*   h1b = (u16*)(ws + OFF_H1);
  float* h1f = (float*)(ws + OFF_H1F);
  u16*   xe  = (u16*)(ws + OFF_XE);
  u16*   X0p = (u16*)(ws + OFF_X0);
  u32*   flg = (u32*)(ws + OFF_FLG);

  // zero h double-buffers + h1f every call (replays must be identical)
  hipMemsetAsync(ws + OFF_H0, 0, OFF_XE - OFF_H0, stream);

  prep_w_kernel<<<16384, 256, 0, stream>>>(Wi0, Wh0, Wi1, Wh1, wbf);
  prep_b_kernel<<<16, 256, 0, stream>>>(bi0, bh0, bi1, bh1, b0v, b1v);
  embed_kernel<<<16384, 256, 0, stream>>>(x, emb, xe);
  x0_gemm_kernel<<<dim3(32, 128), 256, 0, stream>>>(xe, wbf, b0v, X0p);

  // xe tail is dead now -> becomes the padded barrier-flag region (zeroed per call)
  hipMemsetAsync(ws + OFF_FLG, 0, 32768, stream);

  hipFuncSetAttribute((const void*)lstm_kernel,
                      hipFuncAttributeMaxDynamicSharedMemorySize, 104448);
  lstm_kernel<<<256, 256, 104448, stream>>>(wbf, b1v, X0p, h0b, h1b, h1f, flg);

  fc_kernel<<<4000, 256, 0, stream>>>(h1f, fcw, fcb, out);
}

// Round 7
// 4097.511 us; speedup vs baseline: 6.3999x; 1.1026x over previous
//
#include <hip/hip_runtime.h>
#include <hip/hip_bf16.h>

typedef __attribute__((ext_vector_type(8))) short short8;
typedef __attribute__((ext_vector_type(4))) float f32x4;
typedef unsigned short u16;
typedef unsigned int u32;
typedef unsigned long long u64;

#define MFMA_BF16(a, b, c) __builtin_amdgcn_mfma_f32_16x16x32_bf16((a), (b), (c), 0, 0, 0)

// ---------------- workspace layout (bytes) ----------------
static constexpr size_t OFF_W   = 0;                       // 4 x [4096][1024] bf16 = 32MB
static constexpr size_t OFF_B0  = 33554432;                // 4096 f32 (bi0+bh0)
static constexpr size_t OFF_B1  = OFF_B0 + 16384;          // 4096 f32 (bi1+bh1)
static constexpr size_t OFF_H0  = OFF_B1 + 16384;          // 2 init h-slots (2 x 128KB, zeroed)
static constexpr size_t OFF_H1F = OFF_H0 + 262144;         // [32][1024] f32 (final h1)
static constexpr size_t OFF_XE  = OFF_H1F + 131072;        // [16384][1024] bf16 = 32MB
static constexpr size_t OFF_X0  = OFF_XE + 33554432;       // [16384][4096] bf16 = 128MB (also slot arena)
static constexpr size_t WS_NEED = OFF_X0 + 134217728;      // ~192.5 MB
// barrier flags: 256 x 128B = 32KB, overlaid on the TAIL of xe (dead after x0_gemm)
static constexpr size_t OFF_FLG = OFF_X0 - 32768;

// h slot scheme: slot(i) holds {h0[t=i] (32K u16), h1[t=i-1] (32K u16)}, written at
// iteration i via SYSTEM-scope bypass stores (land in MALL, never dirty any L2), read
// at iteration i+1 via NORMAL cached loads (XCD-local L2 amplifies the broadcast).
// slot(-1)=hinit, slot(0)=hinit+64K u16, slot(i>=1) = X0 + (i-1)*128K u16 — the X0
// slice consumed at iteration i-1. Every slot address is L2-allocated at most ONCE
// (X0 gate reads are bypass too), so cached reads can never hit a stale line.

// ---------------- helpers ----------------
__device__ __forceinline__ u16 f2bf(float f) {
  u32 x = __builtin_bit_cast(u32, f);
  x += 0x7fffu + ((x >> 16) & 1u);   // RNE (inputs are finite)
  return (u16)(x >> 16);
}
__device__ __forceinline__ float bf2f(u16 u) {
  return __builtin_bit_cast(float, (u32)u << 16);
}
__device__ __forceinline__ float sigm(float x) { return 1.f / (1.f + expf(-x)); }

// system-scope (MALL-coherent) relaxed ops
__device__ __forceinline__ void sysstore64(void* p, u64 v) {
  __hip_atomic_store((u64*)p, v, __ATOMIC_RELAXED, __HIP_MEMORY_SCOPE_SYSTEM);
}
__device__ __forceinline__ u16 sysload16(const u16* p) {
  return __hip_atomic_load(p, __ATOMIC_RELAXED, __HIP_MEMORY_SCOPE_SYSTEM);
}

__device__ __forceinline__ void gload_lds16(const u16* gsrc, u16* ldst) {
  __builtin_amdgcn_global_load_lds(
      (__attribute__((address_space(1))) void*)(u16*)gsrc,
      (__attribute__((address_space(3))) void*)ldst, 16, 0, 0);
}

// ---------------- prep: fp32 weights -> bf16 ----------------
__global__ void prep_w_kernel(const float* __restrict__ Wi0, const float* __restrict__ Wh0,
                              const float* __restrict__ Wi1, const float* __restrict__ Wh1,
                              u16* __restrict__ dst) {
  size_t e = ((size_t)blockIdx.x * 256 + threadIdx.x) * 4;   // 16M elements total
  int mat = (int)(e >> 22);
  size_t off = e & ((1ull << 22) - 1);
  const float* src = (mat == 0) ? Wi0 : (mat == 1) ? Wh0 : (mat == 2) ? Wi1 : Wh1;
  float4 v = *(const float4*)(src + off);
  ushort4 o;
  o.x = f2bf(v.x); o.y = f2bf(v.y); o.z = f2bf(v.z); o.w = f2bf(v.w);
  *(ushort4*)(dst + e) = o;
}

__global__ void prep_b_kernel(const float* __restrict__ bi0, const float* __restrict__ bh0,
                              const float* __restrict__ bi1, const float* __restrict__ bh1,
                              float* __restrict__ b0, float* __restrict__ b1) {
  int i = blockIdx.x * 256 + threadIdx.x;   // 4096
  b0[i] = bi0[i] + bh0[i];
  b1[i] = bi1[i] + bh1[i];
}

// ---------------- embedding gather ----------------
__global__ void embed_kernel(const int* __restrict__ x, const float* __restrict__ emb,
                             u16* __restrict__ xe) {
  int m = blockIdx.x;            // m = t*32 + b
  int b = m & 31, t = m >> 5;
  int id = x[b * 512 + t];
  float4 v = ((const float4*)(emb + (size_t)id * 1024))[threadIdx.x];
  ushort4 o;
  o.x = f2bf(v.x); o.y = f2bf(v.y); o.z = f2bf(v.z); o.w = f2bf(v.w);
  *(ushort4*)(xe + (size_t)m * 1024 + threadIdx.x * 4) = o;
}

// ---------------- X0 GEMM: [16384,1024] x [4096,1024]^T -> bf16 [16384][4096] (+bias) ----------------
__global__ void x0_gemm_kernel(const u16* __restrict__ A, const u16* __restrict__ W,
                               const float* __restrict__ bias, u16* __restrict__ C) {
  __shared__ u16 lds[2][2][8192];   // [buf][A/B][128 rows x 64 cols]
  const int tid = threadIdx.x, l = tid & 63, w = tid >> 6;
  const int n0 = blockIdx.x * 128, m0 = blockIdx.y * 128;
  const int wm = w >> 1, wn = w & 1;
  const int row8 = l >> 3, u = l & 7;

  f32x4 acc[4][4];
#pragma unroll
  for (int a1 = 0; a1 < 4; ++a1)
#pragma unroll
    for (int a2 = 0; a2 < 4; ++a2) acc[a1][a2] = (f32x4){0.f, 0.f, 0.f, 0.f};

  auto stage = [&](int buf, int kt) {
    const int k0 = kt * 64;
#pragma unroll
    for (int q = 0; q < 4; ++q) {
      const int ld = w * 4 + q;
      const int row = ld * 8 + row8;
      const int sw = (u ^ (row & 7)) * 8;
      gload_lds16(A + (size_t)(m0 + row) * 1024 + k0 + sw, &lds[buf][0][ld * 512]);
      gload_lds16(W + (size_t)(n0 + row) * 1024 + k0 + sw, &lds[buf][1][ld * 512]);
    }
  };

  stage(0, 0);
  __syncthreads();

  for (int kt = 0; kt < 16; ++kt) {
    const int buf = kt & 1;
    if (kt < 15) stage(buf ^ 1, kt + 1);
    const u16* la = lds[buf][0];
    const u16* lb = lds[buf][1];
#pragma unroll
    for (int kk = 0; kk < 2; ++kk) {
      const int c = kk * 4 + (l >> 4);
      const int csw = (c ^ (l & 7)) * 8;    // row&7 == l&7 for all frag rows
      short8 af[4], bf[4];
#pragma unroll
      for (int mi = 0; mi < 4; ++mi) {
        int row = wm * 64 + mi * 16 + (l & 15);
        af[mi] = *(const short8*)(la + row * 64 + csw);
      }
#pragma unroll
      for (int ni = 0; ni < 4; ++ni) {
        int row = wn * 64 + ni * 16 + (l & 15);
        bf[ni] = *(const short8*)(lb + row * 64 + csw);
      }
#pragma unroll
      for (int mi = 0; mi < 4; ++mi)
#pragma unroll
        for (int ni = 0; ni < 4; ++ni)
          acc[mi][ni] = MFMA_BF16(af[mi], bf[ni], acc[mi][ni]);
    }
    __syncthreads();
  }

#pragma unroll
  for (int ni = 0; ni < 4; ++ni) {
    int col = n0 + wn * 64 + ni * 16 + (l & 15);
    float bv = bias[col];
#pragma unroll
    for (int mi = 0; mi < 4; ++mi) {
#pragma unroll
      for (int r = 0; r < 4; ++r) {
        int row = m0 + wm * 64 + mi * 16 + (l >> 4) * 4 + r;
        C[(size_t)row * 4096 + col] = f2bf(acc[mi][ni][r] + bv);
      }
    }
  }
}

// ---------------- persistent recurrent kernel ----------------
// 256 blocks (1/CU), 256 threads (4 waves). Iter i = layer0(t=i) + layer1(t=i-1).
// Proven flat barrier; h via fresh-slot scheme (bypass writes / cached reads).
__launch_bounds__(256, 1)
__global__ void lstm_kernel(const u16* __restrict__ wbf, const float* __restrict__ b1v,
                            const u16* __restrict__ X0, u16* __restrict__ hinit,
                            float* __restrict__ h1f, u32* __restrict__ flags) {
  extern __shared__ char smem[];
  u16* wlds = (u16*)smem;                          // 3 * 16384 u16 = 98304 B
  float* gates0 = (float*)(smem + 98304);          // [32][16]  Wh0.h0
  float* part1  = (float*)(smem + 98304 + 2048);   // [32][16]  Wi1.h0
  float* wh1p   = (float*)(smem + 98304 + 4096);   // [32][16]  Wh1.h1

  const int tid = threadIdx.x;
  const int l = tid & 63, w = tid >> 6;
  const int blk = blockIdx.x;
  const int hbase = blk * 4;
  u16* X0w = (u16*)X0;                             // slot writes into consumed slices

  // ---- fill weight LDS in MFMA fragment order
  for (int m = 0; m < 3; ++m) {
    const u16* Wm = wbf + (size_t)(m + 1) * (4096 * 1024);   // 1=Wh0, 2=Wi1, 3=Wh1
    for (int s = tid; s < 2048; s += 256) {
      int kk = s >> 6, ll = s & 63;
      int nl = ll & 15, hi = ll >> 4;
      int gr = (nl >> 2) * 1024 + hbase + (nl & 3);
      short8 v = *(const short8*)(Wm + (size_t)gr * 1024 + kk * 32 + hi * 8);
      *(short8*)(wlds + m * 16384 + kk * 512 + ll * 8) = v;
    }
  }
  __syncthreads();

  float cst = 0.f;                                 // threads 0..127: c0; 128..255: c1
  const int at = tid & 127, ab = at >> 2, aj = at & 3;
  const int mt = w & 1;

  float b1i = 0.f, b1fv = 0.f, b1g = 0.f, b1o = 0.f;
  if (tid >= 128) {
    b1i  = b1v[hbase + aj];
    b1fv = b1v[1024 + hbase + aj];
    b1g  = b1v[2048 + hbase + aj];
    b1o  = b1v[3072 + hbase + aj];
  }

  const u32* myflag = flags + (size_t)tid * 32;
  u32* ownflag = flags + (size_t)blk * 32;

  for (int i = 0; i <= 512; ++i) {
    // per-iteration slots (u16 units; slot = [h0: 32768][h1: 32768])
    const u16* slot_r = (i == 0) ? hinit
                      : (i == 1) ? hinit + 65536
                                 : X0 + (size_t)(i - 2) * 131072;
    u16* slot_w = (i == 0) ? hinit + 65536
                           : X0w + (size_t)(i - 1) * 131072;

    asm volatile("" ::: "memory");   // pin loads below the previous barrier

    // X0 gate loads: SYSTEM-scope bypass u16 (never allocates in L2 -> slot overlay safe)
    float xg0 = 0.f, xg1 = 0.f, xg2 = 0.f, xg3 = 0.f;
    if (tid < 128 && i < 512) {
      const u16* xp = X0 + (size_t)(i * 32 + ab) * 4096 + hbase + aj;
      xg0 = bf2f(sysload16(xp));
      xg1 = bf2f(sysload16(xp + 1024));
      xg2 = bf2f(sysload16(xp + 2048));
      xg3 = bf2f(sysload16(xp + 3072));
    }

    // ---- preload ALL h fragments: 32 x 16B NORMAL cached loads (L2-amplified broadcast)
    const u16* abase = slot_r + (w < 2 ? 0 : 32768)
                     + (mt * 16 + (l & 15)) * 1024 + ((l >> 4) * 8);
    short8 ar[32];
#pragma unroll
    for (int kk = 0; kk < 32; ++kk)
      ar[kk] = *(const short8*)(abase + kk * 32);

    if (w < 2) {   // waves 0,1: Wh0.h0 and Wi1.h0 (two independent chains each)
      f32x4 a0a = {0,0,0,0}, a0b = {0,0,0,0}, a1a = {0,0,0,0}, a1b = {0,0,0,0};
#pragma unroll
      for (int kk = 0; kk < 16; ++kk) {
        a0a = MFMA_BF16(ar[2 * kk],     *(const short8*)(wlds + (2 * kk) * 512 + l * 8), a0a);
        a1a = MFMA_BF16(ar[2 * kk],     *(const short8*)(wlds + 16384 + (2 * kk) * 512 + l * 8), a1a);
        a0b = MFMA_BF16(ar[2 * kk + 1], *(const short8*)(wlds + (2 * kk + 1) * 512 + l * 8), a0b);
        a1b = MFMA_BF16(ar[2 * kk + 1], *(const short8*)(wlds + 16384 + (2 * kk + 1) * 512 + l * 8), a1b);
      }
#pragma unroll
      for (int r = 0; r < 4; ++r) {
        int row = mt * 16 + (l >> 4) * 4 + r, col = l & 15;
        gates0[row * 16 + col] = a0a[r] + a0b[r];
        part1[row * 16 + col]  = a1a[r] + a1b[r];
      }
    } else {       // waves 2,3: Wh1.h1
      f32x4 a0a = {0,0,0,0}, a0b = {0,0,0,0};
#pragma unroll
      for (int kk = 0; kk < 16; ++kk) {
        a0a = MFMA_BF16(ar[2 * kk],     *(const short8*)(wlds + 2 * 16384 + (2 * kk) * 512 + l * 8), a0a);
        a0b = MFMA_BF16(ar[2 * kk + 1], *(const short8*)(wlds + 2 * 16384 + (2 * kk + 1) * 512 + l * 8), a0b);
      }
#pragma unroll
      for (int r = 0; r < 4; ++r) {
        int row = mt * 16 + (l >> 4) * 4 + r, col = l & 15;
        wh1p[row * 16 + col] = a0a[r] + a0b[r];
      }
    }
    __syncthreads();

    // ---- activations + h slot store (packed 8B system store per 4 dims)
    if (tid < 128) {
      if (i < 512) {
        float gi = gates0[ab * 16 + aj]      + xg0;
        float gf = gates0[ab * 16 + 4 + aj]  + xg1;
        float gg = gates0[ab * 16 + 8 + aj]  + xg2;
        float go = gates0[ab * 16 + 12 + aj] + xg3;
        cst = sigm(gf) * cst + sigm(gi) * tanhf(gg);
        float h = sigm(go) * tanhf(cst);
        u32 hv = (u32)f2bf(h);
        u32 p1 = (u32)__shfl_xor((int)hv, 1);
        u32 lo = (aj & 1) ? ((p1 & 0xffff) | (hv << 16)) : ((hv & 0xffff) | (p1 << 16));
        u32 p2 = (u32)__shfl_xor((int)lo, 2);
        if (aj == 0)
          sysstore64(slot_w + ab * 1024 + hbase, (u64)lo | ((u64)p2 << 32));
      }
    } else {
      if (i >= 1) {
        float gi = part1[ab * 16 + aj]      + wh1p[ab * 16 + aj]      + b1i;
        float gf = part1[ab * 16 + 4 + aj]  + wh1p[ab * 16 + 4 + aj]  + b1fv;
        float gg = part1[ab * 16 + 8 + aj]  + wh1p[ab * 16 + 8 + aj]  + b1g;
        float go = part1[ab * 16 + 12 + aj] + wh1p[ab * 16 + 12 + aj] + b1o;
        cst = sigm(gf) * cst + sigm(gi) * tanhf(gg);
        float h = sigm(go) * tanhf(cst);
        u32 hv = (u32)f2bf(h);
        u32 p1 = (u32)__shfl_xor((int)hv, 1);
        u32 lo = (aj & 1) ? ((p1 & 0xffff) | (hv << 16)) : ((hv & 0xffff) | (p1 << 16));
        u32 p2 = (u32)__shfl_xor((int)lo, 2);
        if (aj == 0)
          sysstore64(slot_w + 32768 + ab * 1024 + hbase, (u64)lo | ((u64)p2 << 32));
        if (i == 512) h1f[ab * 1024 + hbase + aj] = h;
      }
    }

    // ---- flat one-hop grid barrier (proven R2/R3/R6); compiler drains vmcnt before s_barrier,
    // so all slot stores are MALL-visible before the flag posts.
    __syncthreads();
    const u32 target = (u32)(i + 1);
    if (tid == 0)
      __hip_atomic_store(ownflag, target, __ATOMIC_RELAXED, __HIP_MEMORY_SCOPE_SYSTEM);
    while (__hip_atomic_load(myflag, __ATOMIC_RELAXED, __HIP_MEMORY_SCOPE_SYSTEM) < target)
      __builtin_amdgcn_s_sleep(1);
    __syncthreads();
  }
}

// ---------------- final FC ----------------
__global__ void fc_kernel(const float* __restrict__ h1f, const float* __restrict__ fcw,
                          const float* __restrict__ fcb, float* __restrict__ out) {
  int gid = blockIdx.x * 256 + threadIdx.x;
  int v = gid >> 5, b = gid & 31;
  const float4* wr = (const float4*)(fcw + (size_t)v * 1024);
  const float4* hr = (const float4*)(h1f + (size_t)b * 1024);
  float s = 0.f;
#pragma unroll 8
  for (int i = 0; i < 256; ++i) {
    float4 wv = wr[i], hv = hr[i];
    s += wv.x * hv.x + wv.y * hv.y + wv.z * hv.z + wv.w * hv.w;
  }
  out[(size_t)b * 32000 + v] = s + fcb[v];
}

// ---------------- host launch ----------------
extern "C" void kernel_launch(void* const* d_in, const int* in_sizes, int n_in,
                              void* d_out, int out_size, void* d_ws, size_t ws_size,
                              hipStream_t stream) {
  const int*   x   = (const int*)d_in[0];
  const float* emb = (const float*)d_in[1];
  const float* Wi0 = (const float*)d_in[2];
  const float* bi0 = (const float*)d_in[3];
  const float* Wh0 = (const float*)d_in[4];
  const float* bh0 = (const float*)d_in[5];
  const float* Wi1 = (const float*)d_in[6];
  const float* bi1 = (const float*)d_in[7];
  const float* Wh1 = (const float*)d_in[8];
  const float* bh1 = (const float*)d_in[9];
  const float* fcw = (const float*)d_in[10];
  const float* fcb = (const float*)d_in[11];
  float* out = (float*)d_out;
  char* ws = (char*)d_ws;

  if (ws_size < WS_NEED) return;

  u16*   wbf = (u16*)(ws + OFF_W);
  float* b0v = (float*)(ws + OFF_B0);
  float* b1v = (float*)(ws + OFF_B1);
  u16*   hin = (u16*)(ws + OFF_H0);
  float* h1f = (float*)(ws + OFF_H1F);
  u16*   xe  = (u16*)(ws + OFF_XE);
  u16*   X0p = (u16*)(ws + OFF_X0);
  u32*   flg = (u32*)(ws + OFF_FLG);

  // zero init slots + h1f every call (replays must be identical)
  hipMemsetAsync(ws + OFF_H0, 0, OFF_XE - OFF_H0, stream);

  prep_w_kernel<<<16384, 256, 0, stream>>>(Wi0, Wh0, Wi1, Wh1, wbf);
  prep_b_kernel<<<16, 256, 0, stream>>>(bi0, bh0, bi1, bh1, b0v, b1v);
  embed_kernel<<<16384, 256, 0, stream>>>(x, emb, xe);
  x0_gemm_kernel<<<dim3(32, 128), 256, 0, stream>>>(xe, wbf, b0v, X0p);

  // xe tail is dead now -> becomes the padded barrier-flag region (zeroed per call)
  hipMemsetAsync(ws + OFF_FLG, 0, 32768, stream);

  hipFuncSetAttribute((const void*)lstm_kernel,
                      hipFuncAttributeMaxDynamicSharedMemorySize, 104448);
  lstm_kernel<<<256, 256, 104448, stream>>>(wbf, b1v, X0p, hin, h1f, flg);

  fc_kernel<<<4000, 256, 0, stream>>>(h1f, fcw, fcb, out);
}

// Round 8
// 3804.626 us; speedup vs baseline: 6.8926x; 1.0770x over previous
//
#include <hip/hip_runtime.h>
#include <hip/hip_bf16.h>

typedef __attribute__((ext_vector_type(8))) short short8;
typedef __attribute__((ext_vector_type(4))) float f32x4;
typedef __attribute__((ext_vector_type(4))) int i32x4;
typedef unsigned short u16;
typedef unsigned int u32;
typedef unsigned long long u64;

#define MFMA_BF16(a, b, c) __builtin_amdgcn_mfma_f32_16x16x32_bf16((a), (b), (c), 0, 0, 0)

// ---------------- workspace layout (bytes) ----------------
static constexpr size_t OFF_W   = 0;                       // 4 x [4096][1024] bf16 = 32MB
static constexpr size_t OFF_B0  = 33554432;                // 4096 f32 (bi0+bh0)
static constexpr size_t OFF_B1  = OFF_B0 + 16384;          // 4096 f32 (bi1+bh1)
static constexpr size_t OFF_H0  = OFF_B1 + 16384;          // 2 init h-slots (2 x 128KB, zeroed)
static constexpr size_t OFF_H1F = OFF_H0 + 262144;         // [32][1024] f32 (final h1)
static constexpr size_t OFF_XE  = OFF_H1F + 131072;        // [16384][1024] bf16 = 32MB
static constexpr size_t OFF_X0  = OFF_XE + 33554432;       // packed gates Xp = 128MB (also slot arena)
static constexpr size_t WS_NEED = OFF_X0 + 134217728;      // ~192.5 MB
// dense barrier flags: 256 x u32 (1KB), overlaid on xe tail (dead after x0_gemm)
static constexpr size_t OFF_FLG = OFF_X0 - 4096;

// Packed gate layout: Xp[t][blk][b][j][g] (u16), addr = t*131072 + blk*512 + b*16 + j*4 + g.
// Activation thread (b=ab, j=aj) of block blk reads ONE 8B chunk = gates g=0..3.
// h slot scheme (R7, proven): slot(i) = {h0[t=i], h1[t=i-1]}, written at iter i via
// SYSTEM-bypass stores (MALL only, no L2 dirtying), read at iter i+1 via NORMAL cached
// loads (XCD-L2 amplifies). slot(-1)=hinit, slot(0)=hinit+64K u16,
// slot(i>=1) = Xp + (i-1)*131072 (the gate slice bypass-consumed at iter i-1).
// Every slot address is L2-allocated at most ONCE -> cached reads never stale.

// ---------------- helpers ----------------
__device__ __forceinline__ u16 f2bf(float f) {
  u32 x = __builtin_bit_cast(u32, f);
  x += 0x7fffu + ((x >> 16) & 1u);   // RNE (inputs are finite)
  return (u16)(x >> 16);
}
__device__ __forceinline__ float bf2f(u16 u) {
  return __builtin_bit_cast(float, (u32)u << 16);
}
__device__ __forceinline__ float sigm(float x) { return 1.f / (1.f + expf(-x)); }

// system-scope (MALL-coherent) relaxed ops
__device__ __forceinline__ void sysstore64(void* p, u64 v) {
  __hip_atomic_store((u64*)p, v, __ATOMIC_RELAXED, __HIP_MEMORY_SCOPE_SYSTEM);
}
__device__ __forceinline__ u64 sysload64(const void* p) {
  return __hip_atomic_load((const u64*)p, __ATOMIC_RELAXED, __HIP_MEMORY_SCOPE_SYSTEM);
}

__device__ __forceinline__ void gload_lds16(const u16* gsrc, u16* ldst) {
  __builtin_amdgcn_global_load_lds(
      (__attribute__((address_space(1))) void*)(u16*)gsrc,
      (__attribute__((address_space(3))) void*)ldst, 16, 0, 0);
}

// ---------------- prep: fp32 weights -> bf16 ----------------
__global__ void prep_w_kernel(const float* __restrict__ Wi0, const float* __restrict__ Wh0,
                              const float* __restrict__ Wi1, const float* __restrict__ Wh1,
                              u16* __restrict__ dst) {
  size_t e = ((size_t)blockIdx.x * 256 + threadIdx.x) * 4;   // 16M elements total
  int mat = (int)(e >> 22);
  size_t off = e & ((1ull << 22) - 1);
  const float* src = (mat == 0) ? Wi0 : (mat == 1) ? Wh0 : (mat == 2) ? Wi1 : Wh1;
  float4 v = *(const float4*)(src + off);
  ushort4 o;
  o.x = f2bf(v.x); o.y = f2bf(v.y); o.z = f2bf(v.z); o.w = f2bf(v.w);
  *(ushort4*)(dst + e) = o;
}

__global__ void prep_b_kernel(const float* __restrict__ bi0, const float* __restrict__ bh0,
                              const float* __restrict__ bi1, const float* __restrict__ bh1,
                              float* __restrict__ b0, float* __restrict__ b1) {
  int i = blockIdx.x * 256 + threadIdx.x;   // 4096
  b0[i] = bi0[i] + bh0[i];
  b1[i] = bi1[i] + bh1[i];
}

// ---------------- embedding gather ----------------
__global__ void embed_kernel(const int* __restrict__ x, const float* __restrict__ emb,
                             u16* __restrict__ xe) {
  int m = blockIdx.x;            // m = t*32 + b
  int b = m & 31, t = m >> 5;
  int id = x[b * 512 + t];
  float4 v = ((const float4*)(emb + (size_t)id * 1024))[threadIdx.x];
  ushort4 o;
  o.x = f2bf(v.x); o.y = f2bf(v.y); o.z = f2bf(v.z); o.w = f2bf(v.w);
  *(ushort4*)(xe + (size_t)m * 1024 + threadIdx.x * 4) = o;
}

// ---------------- X0 GEMM -> block-packed gate layout Xp (+bias) ----------------
__global__ void x0_gemm_kernel(const u16* __restrict__ A, const u16* __restrict__ W,
                               const float* __restrict__ bias, u16* __restrict__ Xp) {
  __shared__ u16 lds[2][2][8192];   // [buf][A/B][128 rows x 64 cols]
  const int tid = threadIdx.x, l = tid & 63, w = tid >> 6;
  const int n0 = blockIdx.x * 128, m0 = blockIdx.y * 128;
  const int wm = w >> 1, wn = w & 1;
  const int row8 = l >> 3, u = l & 7;

  f32x4 acc[4][4];
#pragma unroll
  for (int a1 = 0; a1 < 4; ++a1)
#pragma unroll
    for (int a2 = 0; a2 < 4; ++a2) acc[a1][a2] = (f32x4){0.f, 0.f, 0.f, 0.f};

  auto stage = [&](int buf, int kt) {
    const int k0 = kt * 64;
#pragma unroll
    for (int q = 0; q < 4; ++q) {
      const int ld = w * 4 + q;
      const int row = ld * 8 + row8;
      const int sw = (u ^ (row & 7)) * 8;
      gload_lds16(A + (size_t)(m0 + row) * 1024 + k0 + sw, &lds[buf][0][ld * 512]);
      gload_lds16(W + (size_t)(n0 + row) * 1024 + k0 + sw, &lds[buf][1][ld * 512]);
    }
  };

  stage(0, 0);
  __syncthreads();

  for (int kt = 0; kt < 16; ++kt) {
    const int buf = kt & 1;
    if (kt < 15) stage(buf ^ 1, kt + 1);
    const u16* la = lds[buf][0];
    const u16* lb = lds[buf][1];
#pragma unroll
    for (int kk = 0; kk < 2; ++kk) {
      const int c = kk * 4 + (l >> 4);
      const int csw = (c ^ (l & 7)) * 8;    // row&7 == l&7 for all frag rows
      short8 af[4], bf[4];
#pragma unroll
      for (int mi = 0; mi < 4; ++mi) {
        int row = wm * 64 + mi * 16 + (l & 15);
        af[mi] = *(const short8*)(la + row * 64 + csw);
      }
#pragma unroll
      for (int ni = 0; ni < 4; ++ni) {
        int row = wn * 64 + ni * 16 + (l & 15);
        bf[ni] = *(const short8*)(lb + row * 64 + csw);
      }
#pragma unroll
      for (int mi = 0; mi < 4; ++mi)
#pragma unroll
        for (int ni = 0; ni < 4; ++ni)
          acc[mi][ni] = MFMA_BF16(af[mi], bf[ni], acc[mi][ni]);
    }
    __syncthreads();
  }

  // epilogue: packed write Xp[t][blkid][b][j][g]
#pragma unroll
  for (int ni = 0; ni < 4; ++ni) {
    int col = n0 + wn * 64 + ni * 16 + (l & 15);
    int g = col >> 10, blkid = (col & 1023) >> 2, j = col & 3;
    float bv = bias[col];
#pragma unroll
    for (int mi = 0; mi < 4; ++mi) {
#pragma unroll
      for (int r = 0; r < 4; ++r) {
        int row = m0 + wm * 64 + mi * 16 + (l >> 4) * 4 + r;
        int t = row >> 5, b = row & 31;
        Xp[(size_t)t * 131072 + blkid * 512 + b * 16 + j * 4 + g] =
            f2bf(acc[mi][ni][r] + bv);
      }
    }
  }
}

// ---------------- persistent recurrent kernel ----------------
// 256 blocks (1/CU), 256 threads (4 waves). Iter i = layer0(t=i) + layer1(t=i-1).
// Dense-flag barrier: writers post 4B system store; wave 0 polls all 256 flags with
// ONE 16B bypass load per lane (4 flags/lane). Gate chunk prefetched under the poll.
__launch_bounds__(256, 1)
__global__ void lstm_kernel(const u16* __restrict__ wbf, const float* __restrict__ b1v,
                            const u16* __restrict__ Xp, u16* __restrict__ hinit,
                            float* __restrict__ h1f, u32* __restrict__ flagsD) {
  extern __shared__ char smem[];
  u16* wlds = (u16*)smem;                          // 3 * 16384 u16 = 98304 B
  float* gates0 = (float*)(smem + 98304);          // [32][16]  Wh0.h0
  float* part1  = (float*)(smem + 98304 + 2048);   // [32][16]  Wi1.h0
  float* wh1p   = (float*)(smem + 98304 + 4096);   // [32][16]  Wh1.h1

  const int tid = threadIdx.x;
  const int l = tid & 63, w = tid >> 6;
  const int blk = blockIdx.x;
  const int hbase = blk * 4;
  u16* Xw = (u16*)Xp;                              // slot writes into consumed gate slices

  // ---- fill weight LDS in MFMA fragment order
  for (int m = 0; m < 3; ++m) {
    const u16* Wm = wbf + (size_t)(m + 1) * (4096 * 1024);   // 1=Wh0, 2=Wi1, 3=Wh1
    for (int s = tid; s < 2048; s += 256) {
      int kk = s >> 6, ll = s & 63;
      int nl = ll & 15, hi = ll >> 4;
      int gr = (nl >> 2) * 1024 + hbase + (nl & 3);
      short8 v = *(const short8*)(Wm + (size_t)gr * 1024 + kk * 32 + hi * 8);
      *(short8*)(wlds + m * 16384 + kk * 512 + ll * 8) = v;
    }
  }
  __syncthreads();

  float cst = 0.f;                                 // threads 0..127: c0; 128..255: c1
  const int at = tid & 127, ab = at >> 2, aj = at & 3;
  const int mt = w & 1;

  float b1i = 0.f, b1fv = 0.f, b1g = 0.f, b1o = 0.f;
  if (tid >= 128) {
    b1i  = b1v[hbase + aj];
    b1fv = b1v[1024 + hbase + aj];
    b1g  = b1v[2048 + hbase + aj];
    b1o  = b1v[3072 + hbase + aj];
  }

  // gate chunk for step 0 (8B bypass; holds gates g=0..3 for this thread's (ab,aj))
  u64 gchunk = 0;
  if (tid < 128)
    gchunk = sysload64(Xp + blk * 512 + ab * 16 + aj * 4);

  const u32* fquad = flagsD + l * 4;               // wave-0 poll: 4 flags per lane

  for (int i = 0; i <= 512; ++i) {
    const u16* slot_r = (i == 0) ? hinit
                      : (i == 1) ? hinit + 65536
                                 : Xp + (size_t)(i - 2) * 131072;
    u16* slot_w = (i == 0) ? hinit + 65536
                           : Xw + (size_t)(i - 1) * 131072;

    asm volatile("" ::: "memory");   // pin loads below the previous barrier

    // ---- preload ALL h fragments: 32 x 16B NORMAL cached loads (L2-amplified broadcast)
    const u16* abase = slot_r + (w < 2 ? 0 : 32768)
                     + (mt * 16 + (l & 15)) * 1024 + ((l >> 4) * 8);
    short8 ar[32];
#pragma unroll
    for (int kk = 0; kk < 32; ++kk)
      ar[kk] = *(const short8*)(abase + kk * 32);

    if (w < 2) {   // waves 0,1: Wh0.h0 and Wi1.h0 (two independent chains each)
      f32x4 a0a = {0,0,0,0}, a0b = {0,0,0,0}, a1a = {0,0,0,0}, a1b = {0,0,0,0};
#pragma unroll
      for (int kk = 0; kk < 16; ++kk) {
        a0a = MFMA_BF16(ar[2 * kk],     *(const short8*)(wlds + (2 * kk) * 512 + l * 8), a0a);
        a1a = MFMA_BF16(ar[2 * kk],     *(const short8*)(wlds + 16384 + (2 * kk) * 512 + l * 8), a1a);
        a0b = MFMA_BF16(ar[2 * kk + 1], *(const short8*)(wlds + (2 * kk + 1) * 512 + l * 8), a0b);
        a1b = MFMA_BF16(ar[2 * kk + 1], *(const short8*)(wlds + 16384 + (2 * kk + 1) * 512 + l * 8), a1b);
      }
#pragma unroll
      for (int r = 0; r < 4; ++r) {
        int row = mt * 16 + (l >> 4) * 4 + r, col = l & 15;
        gates0[row * 16 + col] = a0a[r] + a0b[r];
        part1[row * 16 + col]  = a1a[r] + a1b[r];
      }
    } else {       // waves 2,3: Wh1.h1
      f32x4 a0a = {0,0,0,0}, a0b = {0,0,0,0};
#pragma unroll
      for (int kk = 0; kk < 16; ++kk) {
        a0a = MFMA_BF16(ar[2 * kk],     *(const short8*)(wlds + 2 * 16384 + (2 * kk) * 512 + l * 8), a0a);
        a0b = MFMA_BF16(ar[2 * kk + 1], *(const short8*)(wlds + 2 * 16384 + (2 * kk + 1) * 512 + l * 8), a0b);
      }
#pragma unroll
      for (int r = 0; r < 4; ++r) {
        int row = mt * 16 + (l >> 4) * 4 + r, col = l & 15;
        wh1p[row * 16 + col] = a0a[r] + a0b[r];
      }
    }
    __syncthreads();

    // ---- activations + h slot store (packed 8B system store per 4 dims)
    if (tid < 128) {
      if (i < 512) {
        float gi = gates0[ab * 16 + aj]      + bf2f((u16)(gchunk));
        float gf = gates0[ab * 16 + 4 + aj]  + bf2f((u16)(gchunk >> 16));
        float gg = gates0[ab * 16 + 8 + aj]  + bf2f((u16)(gchunk >> 32));
        float go = gates0[ab * 16 + 12 + aj] + bf2f((u16)(gchunk >> 48));
        cst = sigm(gf) * cst + sigm(gi) * tanhf(gg);
        float h = sigm(go) * tanhf(cst);
        u32 hv = (u32)f2bf(h);
        u32 p1 = (u32)__shfl_xor((int)hv, 1);
        u32 lo = (aj & 1) ? ((p1 & 0xffff) | (hv << 16)) : ((hv & 0xffff) | (p1 << 16));
        u32 p2 = (u32)__shfl_xor((int)lo, 2);
        if (aj == 0)
          sysstore64(slot_w + ab * 1024 + hbase, (u64)lo | ((u64)p2 << 32));
      }
    } else {
      if (i >= 1) {
        float gi = part1[ab * 16 + aj]      + wh1p[ab * 16 + aj]      + b1i;
        float gf = part1[ab * 16 + 4 + aj]  + wh1p[ab * 16 + 4 + aj]  + b1fv;
        float gg = part1[ab * 16 + 8 + aj]  + wh1p[ab * 16 + 8 + aj]  + b1g;
        float go = part1[ab * 16 + 12 + aj] + wh1p[ab * 16 + 12 + aj] + b1o;
        cst = sigm(gf) * cst + sigm(gi) * tanhf(gg);
        float h = sigm(go) * tanhf(cst);
        u32 hv = (u32)f2bf(h);
        u32 p1 = (u32)__shfl_xor((int)hv, 1);
        u32 lo = (aj & 1) ? ((p1 & 0xffff) | (hv << 16)) : ((hv & 0xffff) | (p1 << 16));
        u32 p2 = (u32)__shfl_xor((int)lo, 2);
        if (aj == 0)
          sysstore64(slot_w + 32768 + ab * 1024 + hbase, (u64)lo | ((u64)p2 << 32));
        if (i == 512) h1f[ab * 1024 + hbase + aj] = h;
      }
    }

    if (i == 512) break;                 // done; no final barrier needed

    // ---- dense-flag barrier: post, prefetch gates, wave-0 poll
    __syncthreads();                     // all h system-stores drained (vmcnt 0, all waves)
    const u32 target = (u32)(i + 1);
    if (tid == 0)
      __hip_atomic_store(&flagsD[blk], target, __ATOMIC_RELAXED, __HIP_MEMORY_SCOPE_SYSTEM);

    // prefetch next step's gate chunk under the barrier wait
    if (tid < 128 && i + 1 < 512)
      gchunk = sysload64(Xp + (size_t)(i + 1) * 131072 + blk * 512 + ab * 16 + aj * 4);

    if (w == 0) {                        // 64 lanes x 4 flags = all 256, one 16B load/lane
      while (true) {
        i32x4 v;
        asm volatile("global_load_dwordx4 %0, %1, off sc0 sc1"
                     : "=&v"(v) : "v"(fquad));
        asm volatile("s_waitcnt vmcnt(0)" ::: "memory");
        u32 m01 = min((u32)v.x, (u32)v.y);
        u32 m23 = min((u32)v.z, (u32)v.w);
        if (__all(min(m01, m23) >= target)) break;
      }
    }
    __syncthreads();                     // whole block proceeds once wave 0 confirms
  }
}

// ---------------- final FC ----------------
__global__ void fc_kernel(const float* __restrict__ h1f, const float* __restrict__ fcw,
                          const float* __restrict__ fcb, float* __restrict__ out) {
  int gid = blockIdx.x * 256 + threadIdx.x;
  int v = gid >> 5, b = gid & 31;
  const float4* wr = (const float4*)(fcw + (size_t)v * 1024);
  const float4* hr = (const float4*)(h1f + (size_t)b * 1024);
  float s = 0.f;
#pragma unroll 8
  for (int i = 0; i < 256; ++i) {
    float4 wv = wr[i], hv = hr[i];
    s += wv.x * hv.x + wv.y * hv.y + wv.z * hv.z + wv.w * hv.w;
  }
  out[(size_t)b * 32000 + v] = s + fcb[v];
}

// ---------------- host launch ----------------
extern "C" void kernel_launch(void* const* d_in, const int* in_sizes, int n_in,
                              void* d_out, int out_size, void* d_ws, size_t ws_size,
                              hipStream_t stream) {
  const int*   x   = (const int*)d_in[0];
  const float* emb = (const float*)d_in[1];
  const float* Wi0 = (const float*)d_in[2];
  const float* bi0 = (const float*)d_in[3];
  const float* Wh0 = (const float*)d_in[4];
  const float* bh0 = (const float*)d_in[5];
  const float* Wi1 = (const float*)d_in[6];
  const float* bi1 = (const float*)d_in[7];
  const float* Wh1 = (const float*)d_in[8];
  const float* bh1 = (const float*)d_in[9];
  const float* fcw = (const float*)d_in[10];
  const float* fcb = (const float*)d_in[11];
  float* out = (float*)d_out;
  char* ws = (char*)d_ws;

  if (ws_size < WS_NEED) return;

  u16*   wbf = (u16*)(ws + OFF_W);
  float* b0v = (float*)(ws + OFF_B0);
  float* b1v = (float*)(ws + OFF_B1);
  u16*   hin = (u16*)(ws + OFF_H0);
  float* h1f = (float*)(ws + OFF_H1F);
  u16*   xe  = (u16*)(ws + OFF_XE);
  u16*   Xp  = (u16*)(ws + OFF_X0);
  u32*   flg = (u32*)(ws + OFF_FLG);

  // zero init slots + h1f every call (replays must be identical)
  hipMemsetAsync(ws + OFF_H0, 0, OFF_XE - OFF_H0, stream);

  prep_w_kernel<<<16384, 256, 0, stream>>>(Wi0, Wh0, Wi1, Wh1, wbf);
  prep_b_kernel<<<16, 256, 0, stream>>>(bi0, bh0, bi1, bh1, b0v, b1v);
  embed_kernel<<<16384, 256, 0, stream>>>(x, emb, xe);
  x0_gemm_kernel<<<dim3(32, 128), 256, 0, stream>>>(xe, wbf, b0v, Xp);

  // xe tail is dead now -> dense barrier flags (zeroed per call)
  hipMemsetAsync(ws + OFF_FLG, 0, 4096, stream);

  hipFuncSetAttribute((const void*)lstm_kernel,
                      hipFuncAttributeMaxDynamicSharedMemorySize, 104448);
  lstm_kernel<<<256, 256, 104448, stream>>>(wbf, b1v, Xp, hin, h1f, flg);

  fc_kernel<<<4000, 256, 0, stream>>>(h1f, fcw, fcb, out);
}